// Round 3
// baseline (90165.454 us; speedup 1.0000x reference)
//
#include <hip/hip_runtime.h>

#define HID 128
#define ET 64          // edges (or nodes) per block
#define WO 32          // output columns per wave
#define NEDGE 800000
#define NNODE 50000
#define NGRAPH 64

__device__ __forceinline__ float silu_f(float x) {
    // x * sigmoid(x); identical numerics to the passing round-2 kernel
    return x * __frcp_rn(1.0f + __expf(-x));
}

// ---- pipelined-chunk helpers -----------------------------------------------
// One weight chunk = 16 k-rows x 128 cols = 8KB. 256 threads stage it:
// thread tid covers floats [tid*8, tid*8+8)  (two float4 = 32B, coalesced).
__device__ __forceinline__ void wload(float4& s0, float4& s1,
                                      const float* __restrict__ W, int chunk, int tid) {
    const float* p = W + (size_t)chunk * (16 * HID) + tid * 8;
    s0 = *reinterpret_cast<const float4*>(p);
    s1 = *reinterpret_cast<const float4*>(p + 4);
}
__device__ __forceinline__ void wstore(float* buf, int tid,
                                       const float4& s0, const float4& s1) {
    float* q = buf + tid * 8;
    *reinterpret_cast<float4*>(q) = s0;
    *reinterpret_cast<float4*>(q + 4) = s1;
}
// 16 consecutive floats (one act chunk) -> registers
__device__ __forceinline__ void load_act16(float* dst, const float* __restrict__ src) {
#pragma unroll
    for (int q = 0; q < 4; ++q)
        *reinterpret_cast<float4*>(dst + 4 * q) =
            *reinterpret_cast<const float4*>(src + 4 * q);
}
// acc[t] += sum_kk a16[kk] * w[kk][o0+t]; w reads are wave-uniform -> LDS broadcast
__device__ __forceinline__ void chunk_fma(float* __restrict__ acc,
                                          const float* __restrict__ wslice,
                                          const float* __restrict__ a16) {
#pragma unroll
    for (int kk = 0; kk < 16; ++kk) {
        const float a = a16[kk];
        const float* wr = wslice + kk * HID;
#pragma unroll
        for (int t = 0; t < WO; ++t) acc[t] = fmaf(a, wr[t], acc[t]);
    }
}

// ---------------------------------------------------------------------------
// K0: zero agg_msg workspace, copy pos -> out_pos (atomics add onto it later)
// ---------------------------------------------------------------------------
__global__ __launch_bounds__(256) void init_kernel(const float* __restrict__ pos,
                                                   float* __restrict__ agg,
                                                   float* __restrict__ out_pos) {
    const int tid = blockIdx.x * blockDim.x + threadIdx.x;
    const int stride = gridDim.x * blockDim.x;
    float4* a4 = reinterpret_cast<float4*>(agg);
    const int nAgg4 = NNODE * HID / 4;
    for (int i = tid; i < nAgg4; i += stride) a4[i] = make_float4(0.f, 0.f, 0.f, 0.f);
    const float4* p4 = reinterpret_cast<const float4*>(pos);
    float4* o4 = reinterpret_cast<float4*>(out_pos);
    const int nPos4 = NNODE * 3 / 4;
    for (int i = tid; i < nPos4; i += stride) o4[i] = p4[i];
}

// ---------------------------------------------------------------------------
// K1: film = cond @ W_film + b_film   [64,128]@[128,256]
// ---------------------------------------------------------------------------
__global__ __launch_bounds__(256) void film_kernel(const float* __restrict__ cond,
                                                   const float* __restrict__ Wf,
                                                   const float* __restrict__ bf,
                                                   float* __restrict__ film) {
    const int g = blockIdx.x;
    const int o = threadIdx.x;
    const float* __restrict__ cg = cond + g * 128;
    float acc = bf[o];
    for (int k = 0; k < 128; ++k) acc = fmaf(cg[k], Wf[k * 256 + o], acc);
    film[g * 256 + o] = acc;
}

// ---------------------------------------------------------------------------
// K2: edge kernel — msg MLP (2 layers) + coord MLP, scatter-add at the end
// ---------------------------------------------------------------------------
__global__ __launch_bounds__(256, 3) void edge_kernel(
    const float* __restrict__ h, const float* __restrict__ pos,
    const float* __restrict__ edge_attr, const int* __restrict__ eidx,
    const float* __restrict__ W1, const float* __restrict__ b1,
    const float* __restrict__ W2, const float* __restrict__ b2,
    const float* __restrict__ Wc1, const float* __restrict__ bc1,
    const float* __restrict__ Wc2,
    float* __restrict__ agg_msg, float* __restrict__ out_pos) {
    __shared__ float wbuf[2][16 * HID];       // 16 KB weight double-buffer
    __shared__ float m_lds[ET][HID + 4];      // +4 pad: 16B-aligned b128, ~8/bank
    __shared__ float cw_part[4][ET];

    const int tid = threadIdx.x;
    const int lane = tid & 63;
    const int wv = tid >> 6;
    const int o0 = __builtin_amdgcn_readfirstlane(wv << 5);

    const int e = blockIdx.x * ET + lane;     // NEDGE % ET == 0
    const int ni = eidx[e];
    const int nj = eidx[NEDGE + e];

    const float pix = pos[ni * 3 + 0], piy = pos[ni * 3 + 1], piz = pos[ni * 3 + 2];
    const float pjx = pos[nj * 3 + 0], pjy = pos[nj * 3 + 1], pjz = pos[nj * 3 + 2];
    const float rx = pix - pjx, ry = piy - pjy, rz = piz - pjz;
    const float d2 = rx * rx + ry * ry + rz * rz;

    const float* __restrict__ hi = h + (size_t)ni * HID;
    const float* __restrict__ hj = h + (size_t)nj * HID;

    alignas(16) float ea[16];
    load_act16(ea, edge_attr + (size_t)e * 16);

    float accA[WO], accM[WO];

    // ---- accA init: bias + dist_sq row + edge_attr rows (k = 256..272) ----
    {
        const float* b = b1 + o0;
        const float* wd = W1 + (size_t)256 * HID + o0;
#pragma unroll
        for (int t = 0; t < WO; ++t) accA[t] = b[t] + d2 * wd[t];
#pragma unroll
        for (int q = 0; q < 16; ++q) {
            const float* wq = W1 + (size_t)(257 + q) * HID + o0;
            const float a = ea[q];
#pragma unroll
            for (int t = 0; t < WO; ++t) accA[t] = fmaf(a, wq[t], accA[t]);
        }
    }

    // ---- layer 1: k = 0..255 in 16 chunks (0-7: h_i, 8-15: h_j) ----
    float4 s0, s1;
    alignas(16) float aA[16], aB[16];
    wload(s0, s1, W1, 0, tid);
    load_act16(aA, hi);
    wstore(wbuf[0], tid, s0, s1);
    __syncthreads();
#pragma unroll 1
    for (int c = 0; c < 16; c += 2) {
        wload(s0, s1, W1, c + 1, tid);                     // stage next (in flight)
        load_act16(aB, (c + 1 < 8) ? hi + (c + 1) * 16 : hj + (c + 1 - 8) * 16);
        chunk_fma(accA, &wbuf[0][o0], aA);                 // compute current
        wstore(wbuf[1], tid, s0, s1);                      // (vmcnt wait auto)
        __syncthreads();
        if (c + 2 < 16) {
            wload(s0, s1, W1, c + 2, tid);
            load_act16(aA, (c + 2 < 8) ? hi + (c + 2) * 16 : hj + (c + 2 - 8) * 16);
        }
        chunk_fma(accA, &wbuf[1][o0], aB);
        if (c + 2 < 16) wstore(wbuf[0], tid, s0, s1);
        __syncthreads();
    }

    // ---- layer 2: m_ij = silu(m @ W2 + b2) ----
#pragma unroll
    for (int t = 0; t < WO; ++t) accA[t] = silu_f(accA[t]);
    wload(s0, s1, W2, 0, tid);
    {
        float* mr = &m_lds[lane][o0];
#pragma unroll
        for (int t = 0; t < WO; ++t) mr[t] = accA[t];
    }
    {
        const float* b = b2 + o0;
#pragma unroll
        for (int t = 0; t < WO; ++t) accM[t] = b[t];
    }
    wstore(wbuf[0], tid, s0, s1);
    __syncthreads();
#pragma unroll 1
    for (int c = 0; c < 8; c += 2) {
        wload(s0, s1, W2, c + 1, tid);
        chunk_fma(accM, &wbuf[0][o0], &m_lds[lane][c * 16]);
        wstore(wbuf[1], tid, s0, s1);
        __syncthreads();
        if (c + 2 < 8) wload(s0, s1, W2, c + 2, tid);
        chunk_fma(accM, &wbuf[1][o0], &m_lds[lane][(c + 1) * 16]);
        if (c + 2 < 8) wstore(wbuf[0], tid, s0, s1);
        __syncthreads();
    }
#pragma unroll
    for (int t = 0; t < WO; ++t) accM[t] = silu_f(accM[t]);   // accM = m_ij slice

    // ---- layer 3: coord_w = silu(m_ij @ Wc1 + bc1) @ Wc2 ----
    wload(s0, s1, Wc1, 0, tid);
    {   // overwrite m_lds with m_ij (all reads of m finished at last barrier)
        float* mr = &m_lds[lane][o0];
#pragma unroll
        for (int t = 0; t < WO; ++t) mr[t] = accM[t];
    }
    {
        const float* b = bc1 + o0;
#pragma unroll
        for (int t = 0; t < WO; ++t) accA[t] = b[t];
    }
    wstore(wbuf[0], tid, s0, s1);
    __syncthreads();
#pragma unroll 1
    for (int c = 0; c < 8; c += 2) {
        wload(s0, s1, Wc1, c + 1, tid);
        chunk_fma(accA, &wbuf[0][o0], &m_lds[lane][c * 16]);
        wstore(wbuf[1], tid, s0, s1);
        __syncthreads();
        if (c + 2 < 8) wload(s0, s1, Wc1, c + 2, tid);
        chunk_fma(accA, &wbuf[1][o0], &m_lds[lane][(c + 1) * 16]);
        if (c + 2 < 8) wstore(wbuf[0], tid, s0, s1);
        __syncthreads();
    }

    float cw = 0.f;
    {
        const float* w2p = Wc2 + o0;
#pragma unroll
        for (int t = 0; t < WO; ++t) cw += silu_f(accA[t]) * w2p[t];
    }
    cw_part[wv][lane] = cw;
    __syncthreads();

    if (wv == 0) {
        const float cwf = cw_part[0][lane] + cw_part[1][lane] +
                          cw_part[2][lane] + cw_part[3][lane];
        const float s = cwf / sqrtf(d2 + 1e-8f);
        float* op = out_pos + (size_t)ni * 3;
        atomicAdd(op + 0, rx * s);
        atomicAdd(op + 1, ry * s);
        atomicAdd(op + 2, rz * s);
    }

    // ---- final: m_ij scatter (fire-and-forget, no trailing barrier) ----
    {
        float* am = agg_msg + (size_t)ni * HID + o0;
#pragma unroll
        for (int t = 0; t < WO; ++t) atomicAdd(am + t, accM[t]);
    }
}

// ---------------------------------------------------------------------------
// K3: node kernel — node MLP + FiLM + residual + LayerNorm (same pipeline)
// ---------------------------------------------------------------------------
__global__ __launch_bounds__(256, 3) void node_kernel(
    const float* __restrict__ h, const float* __restrict__ agg_msg,
    const float* __restrict__ film, const int* __restrict__ batch,
    const float* __restrict__ Wn1, const float* __restrict__ bn1,
    const float* __restrict__ Wn2, const float* __restrict__ bn2,
    const float* __restrict__ lng, const float* __restrict__ lnb,
    float* __restrict__ out_h) {
    __shared__ float wbuf[2][16 * HID];
    __shared__ float u_lds[ET][HID + 4];
    __shared__ float red[2][4][ET];

    const int tid = threadIdx.x;
    const int lane = tid & 63;
    const int wv = tid >> 6;
    const int o0 = __builtin_amdgcn_readfirstlane(wv << 5);

    const int n = blockIdx.x * ET + lane;
    const bool valid = (n < NNODE);
    const int nc = valid ? n : (NNODE - 1);

    const float* __restrict__ hr = h + (size_t)nc * HID;
    const float* __restrict__ ar = agg_msg + (size_t)nc * HID;

    float accA[WO], accM[WO];
    float4 s0, s1;
    alignas(16) float aA[16], aB[16];

    // ---- layer 1: silu([h, agg] @ Wn1 + bn1), 16 chunks (0-7 h, 8-15 agg) ----
    {
        const float* b = bn1 + o0;
#pragma unroll
        for (int t = 0; t < WO; ++t) accA[t] = b[t];
    }
    wload(s0, s1, Wn1, 0, tid);
    load_act16(aA, hr);
    wstore(wbuf[0], tid, s0, s1);
    __syncthreads();
#pragma unroll 1
    for (int c = 0; c < 16; c += 2) {
        wload(s0, s1, Wn1, c + 1, tid);
        load_act16(aB, (c + 1 < 8) ? hr + (c + 1) * 16 : ar + (c + 1 - 8) * 16);
        chunk_fma(accA, &wbuf[0][o0], aA);
        wstore(wbuf[1], tid, s0, s1);
        __syncthreads();
        if (c + 2 < 16) {
            wload(s0, s1, Wn1, c + 2, tid);
            load_act16(aA, (c + 2 < 8) ? hr + (c + 2) * 16 : ar + (c + 2 - 8) * 16);
        }
        chunk_fma(accA, &wbuf[1][o0], aB);
        if (c + 2 < 16) wstore(wbuf[0], tid, s0, s1);
        __syncthreads();
    }

    // ---- layer 2: hn = u @ Wn2 + bn2 ----
    wload(s0, s1, Wn2, 0, tid);
    {
        float* ur = &u_lds[lane][o0];
#pragma unroll
        for (int t = 0; t < WO; ++t) ur[t] = silu_f(accA[t]);
    }
    {
        const float* b = bn2 + o0;
#pragma unroll
        for (int t = 0; t < WO; ++t) accM[t] = b[t];
    }
    wstore(wbuf[0], tid, s0, s1);
    __syncthreads();
#pragma unroll 1
    for (int c = 0; c < 8; c += 2) {
        wload(s0, s1, Wn2, c + 1, tid);
        chunk_fma(accM, &wbuf[0][o0], &u_lds[lane][c * 16]);
        wstore(wbuf[1], tid, s0, s1);
        __syncthreads();
        if (c + 2 < 8) wload(s0, s1, Wn2, c + 2, tid);
        chunk_fma(accM, &wbuf[1][o0], &u_lds[lane][(c + 1) * 16]);
        if (c + 2 < 8) wstore(wbuf[0], tid, s0, s1);
        __syncthreads();
    }

    // ---- FiLM + residual + LayerNorm ----
    const int g = batch[nc];
    const float* fg = film + (size_t)g * 256;
    float x[WO];
    float s1r = 0.f;
#pragma unroll
    for (int t = 0; t < WO; ++t) {
        const float v = hr[o0 + t] + fmaf(fg[o0 + t], accM[t], fg[128 + o0 + t]);
        x[t] = v;
        s1r += v;
    }
    red[0][wv][lane] = s1r;
    __syncthreads();
    const float mu = (red[0][0][lane] + red[0][1][lane] +
                      red[0][2][lane] + red[0][3][lane]) * (1.f / 128.f);
    float s2r = 0.f;
#pragma unroll
    for (int t = 0; t < WO; ++t) {
        const float d = x[t] - mu;
        s2r += d * d;
    }
    red[1][wv][lane] = s2r;
    __syncthreads();
    const float var = (red[1][0][lane] + red[1][1][lane] +
                       red[1][2][lane] + red[1][3][lane]) * (1.f / 128.f);
    const float rstd = 1.0f / sqrtf(var + 1e-5f);

    if (valid) {
        float* orow = out_h + (size_t)n * HID + o0;
#pragma unroll
        for (int t = 0; t < WO; ++t)
            orow[t] = (x[t] - mu) * rstd * lng[o0 + t] + lnb[o0 + t];
    }
}

// ---------------------------------------------------------------------------
extern "C" void kernel_launch(void* const* d_in, const int* in_sizes, int n_in,
                              void* d_out, int out_size, void* d_ws, size_t ws_size,
                              hipStream_t stream) {
    const float* h    = (const float*)d_in[0];
    const float* pos  = (const float*)d_in[1];
    const float* ea   = (const float*)d_in[2];
    const float* cond = (const float*)d_in[3];
    const int*   eidx = (const int*)d_in[4];
    const int*   batch= (const int*)d_in[5];
    const float* W1   = (const float*)d_in[6];
    const float* b1   = (const float*)d_in[7];
    const float* W2   = (const float*)d_in[8];
    const float* b2   = (const float*)d_in[9];
    const float* Wc1  = (const float*)d_in[10];
    const float* bc1  = (const float*)d_in[11];
    const float* Wc2  = (const float*)d_in[12];
    const float* Wn1  = (const float*)d_in[13];
    const float* bn1  = (const float*)d_in[14];
    const float* Wn2  = (const float*)d_in[15];
    const float* bn2  = (const float*)d_in[16];
    const float* Wf   = (const float*)d_in[17];
    const float* bf   = (const float*)d_in[18];
    const float* lng  = (const float*)d_in[19];
    const float* lnb  = (const float*)d_in[20];

    float* out_h   = (float*)d_out;                        // [N,128]
    float* out_pos = out_h + (size_t)NNODE * HID;          // [N,3]
    float* agg_msg = (float*)d_ws;                         // [N,128] scratch
    float* film    = agg_msg + (size_t)NNODE * HID;        // [64,256] scratch

    init_kernel<<<2048, 256, 0, stream>>>(pos, agg_msg, out_pos);
    film_kernel<<<NGRAPH, 256, 0, stream>>>(cond, Wf, bf, film);
    edge_kernel<<<NEDGE / ET, 256, 0, stream>>>(h, pos, ea, eidx,
                                                W1, b1, W2, b2, Wc1, bc1, Wc2,
                                                agg_msg, out_pos);
    node_kernel<<<(NNODE + ET - 1) / ET, 256, 0, stream>>>(h, agg_msg, film, batch,
                                                           Wn1, bn1, Wn2, bn2,
                                                           lng, lnb, out_h);
}

// Round 4
// 8097.301 us; speedup vs baseline: 11.1352x; 11.1352x over previous
//
#include <hip/hip_runtime.h>

#define HID 128
#define ET 64          // edges (or nodes) per block
#define WO 32          // output columns per wave
#define NEDGE 800000
#define NNODE 50000
#define NGRAPH 64

__device__ __forceinline__ float silu_f(float x) {
    return x * __frcp_rn(1.0f + __expf(-x));
}

// acc[t] += a{x,y,z,w} * w[k][o0+t] for 4 consecutive k rows (row stride HID).
// NOTE: w's address is derived from tid (divergent to the compiler) -> VMEM
// vector loads (same-address broadcast within wave), NOT s_load. This is the
// whole point: the scalar-cache path serialized r2 at VALUBusy=15%.
__device__ __forceinline__ void gemv4(float* __restrict__ acc,
                                      float ax, float ay, float az, float aw,
                                      const float* __restrict__ w) {
#pragma unroll
    for (int t = 0; t < WO; ++t) acc[t] = fmaf(ax, w[t], acc[t]);
#pragma unroll
    for (int t = 0; t < WO; ++t) acc[t] = fmaf(ay, w[HID + t], acc[t]);
#pragma unroll
    for (int t = 0; t < WO; ++t) acc[t] = fmaf(az, w[2 * HID + t], acc[t]);
#pragma unroll
    for (int t = 0; t < WO; ++t) acc[t] = fmaf(aw, w[3 * HID + t], acc[t]);
}

// ---------------------------------------------------------------------------
// K0: zero agg_msg workspace, copy pos -> out_pos (atomics add onto it later)
// ---------------------------------------------------------------------------
__global__ __launch_bounds__(256) void init_kernel(const float* __restrict__ pos,
                                                   float* __restrict__ agg,
                                                   float* __restrict__ out_pos) {
    const int tid = blockIdx.x * blockDim.x + threadIdx.x;
    const int stride = gridDim.x * blockDim.x;
    float4* a4 = reinterpret_cast<float4*>(agg);
    const int nAgg4 = NNODE * HID / 4;
    for (int i = tid; i < nAgg4; i += stride) a4[i] = make_float4(0.f, 0.f, 0.f, 0.f);
    const float4* p4 = reinterpret_cast<const float4*>(pos);
    float4* o4 = reinterpret_cast<float4*>(out_pos);
    const int nPos4 = NNODE * 3 / 4;
    for (int i = tid; i < nPos4; i += stride) o4[i] = p4[i];
}

// ---------------------------------------------------------------------------
// K1: film = cond @ W_film + b_film   [64,128]@[128,256]
// ---------------------------------------------------------------------------
__global__ __launch_bounds__(256) void film_kernel(const float* __restrict__ cond,
                                                   const float* __restrict__ Wf,
                                                   const float* __restrict__ bf,
                                                   float* __restrict__ film) {
    const int g = blockIdx.x;
    const int o = threadIdx.x;
    const float* __restrict__ cg = cond + g * 128;
    float acc = bf[o];
    for (int k = 0; k < 128; ++k) acc = fmaf(cg[k], Wf[k * 256 + o], acc);
    film[g * 256 + o] = acc;
}

// ---------------------------------------------------------------------------
// K2: edge kernel — msg MLP (2 layers) + coord MLP, scatter-add at the end
// block = 256 threads = 4 waves; lane = edge within tile, wave = 32-col slice
// ---------------------------------------------------------------------------
__global__ __launch_bounds__(256) void edge_kernel(
    const float* __restrict__ h, const float* __restrict__ pos,
    const float* __restrict__ edge_attr, const int* __restrict__ eidx,
    const float* __restrict__ W1, const float* __restrict__ b1,
    const float* __restrict__ W2, const float* __restrict__ b2,
    const float* __restrict__ Wc1, const float* __restrict__ bc1,
    const float* __restrict__ Wc2,
    float* __restrict__ agg_msg, float* __restrict__ out_pos) {
    __shared__ float m_lds[ET][HID + 1];   // +1 pad: proven zero-conflict in r2
    __shared__ float cw_part[4][ET];

    const int tid = threadIdx.x;
    const int lane = tid & 63;
    const int wv = tid >> 6;
    const int o0 = wv << 5;   // NO readfirstlane: keep divergent -> VMEM loads

    const int e = blockIdx.x * ET + lane;   // NEDGE % ET == 0
    const int ni = eidx[e];
    const int nj = eidx[NEDGE + e];

    const float pix = pos[ni * 3 + 0], piy = pos[ni * 3 + 1], piz = pos[ni * 3 + 2];
    const float pjx = pos[nj * 3 + 0], pjy = pos[nj * 3 + 1], pjz = pos[nj * 3 + 2];
    const float rx = pix - pjx, ry = piy - pjy, rz = piz - pjz;
    const float d2 = rx * rx + ry * ry + rz * rz;

    const float* __restrict__ hi = h + (size_t)ni * HID;
    const float* __restrict__ hj = h + (size_t)nj * HID;

    // ---- layer 1: silu(msg_input @ W1 + b1), K = 273 ----
    float acc[WO];
#pragma unroll
    for (int t = 0; t < WO; ++t) acc[t] = b1[o0 + t];

#pragma unroll 2
    for (int kb = 0; kb < HID; kb += 4) {
        const float4 a = *reinterpret_cast<const float4*>(hi + kb);
        gemv4(acc, a.x, a.y, a.z, a.w, W1 + (size_t)kb * HID + o0);
    }
#pragma unroll 2
    for (int kb = 0; kb < HID; kb += 4) {
        const float4 a = *reinterpret_cast<const float4*>(hj + kb);
        gemv4(acc, a.x, a.y, a.z, a.w, W1 + (size_t)(HID + kb) * HID + o0);
    }
    {   // k = 256 : dist_sq
        const float* __restrict__ w = W1 + (size_t)256 * HID + o0;
#pragma unroll
        for (int t = 0; t < WO; ++t) acc[t] = fmaf(d2, w[t], acc[t]);
    }
    {   // k = 257..272 : edge_attr
        const float* __restrict__ eae = edge_attr + (size_t)e * 16;
#pragma unroll 2
        for (int kb = 0; kb < 16; kb += 4) {
            const float4 a = *reinterpret_cast<const float4*>(eae + kb);
            gemv4(acc, a.x, a.y, a.z, a.w, W1 + (size_t)(257 + kb) * HID + o0);
        }
    }
#pragma unroll
    for (int t = 0; t < WO; ++t) acc[t] = silu_f(acc[t]);

    // exchange m through LDS
#pragma unroll
    for (int t = 0; t < WO; ++t) m_lds[lane][o0 + t] = acc[t];
    __syncthreads();

    // ---- layer 2: m_ij = silu(m @ W2 + b2), K = 128 ----
    float acc2[WO];
#pragma unroll
    for (int t = 0; t < WO; ++t) acc2[t] = b2[o0 + t];
#pragma unroll 2
    for (int kb = 0; kb < HID; kb += 4) {
        const float a0 = m_lds[lane][kb + 0];
        const float a1 = m_lds[lane][kb + 1];
        const float a2 = m_lds[lane][kb + 2];
        const float a3 = m_lds[lane][kb + 3];
        gemv4(acc2, a0, a1, a2, a3, W2 + (size_t)kb * HID + o0);
    }
#pragma unroll
    for (int t = 0; t < WO; ++t) acc2[t] = silu_f(acc2[t]);   // acc2 = m_ij slice

    __syncthreads();   // all reads of m done before overwrite
#pragma unroll
    for (int t = 0; t < WO; ++t) m_lds[lane][o0 + t] = acc2[t];
    __syncthreads();

    // ---- layer 3: coord_w = silu(m_ij @ Wc1 + bc1) @ Wc2, K = 128 ----
    float acc3[WO];
#pragma unroll
    for (int t = 0; t < WO; ++t) acc3[t] = bc1[o0 + t];
#pragma unroll 2
    for (int kb = 0; kb < HID; kb += 4) {
        const float a0 = m_lds[lane][kb + 0];
        const float a1 = m_lds[lane][kb + 1];
        const float a2 = m_lds[lane][kb + 2];
        const float a3 = m_lds[lane][kb + 3];
        gemv4(acc3, a0, a1, a2, a3, Wc1 + (size_t)kb * HID + o0);
    }
    float cw = 0.f;
    {
        const float* __restrict__ w2p = Wc2 + o0;
#pragma unroll
        for (int t = 0; t < WO; ++t) cw += silu_f(acc3[t]) * w2p[t];
    }
    cw_part[wv][lane] = cw;
    __syncthreads();

    if (wv == 0) {
        const float cwf = cw_part[0][lane] + cw_part[1][lane] +
                          cw_part[2][lane] + cw_part[3][lane];
        const float s = cwf / sqrtf(d2 + 1e-8f);
        float* __restrict__ op = out_pos + (size_t)ni * 3;
        atomicAdd(op + 0, rx * s);
        atomicAdd(op + 1, ry * s);
        atomicAdd(op + 2, rz * s);
    }

    // ---- final: m_ij scatter (fire-and-forget, no trailing barrier) ----
    {
        float* __restrict__ am = agg_msg + (size_t)ni * HID + o0;
#pragma unroll
        for (int t = 0; t < WO; ++t) atomicAdd(am + t, acc2[t]);
    }
}

// ---------------------------------------------------------------------------
// K3: node kernel — node MLP + FiLM + residual + LayerNorm
// ---------------------------------------------------------------------------
__global__ __launch_bounds__(256) void node_kernel(
    const float* __restrict__ h, const float* __restrict__ agg_msg,
    const float* __restrict__ film, const int* __restrict__ batch,
    const float* __restrict__ Wn1, const float* __restrict__ bn1,
    const float* __restrict__ Wn2, const float* __restrict__ bn2,
    const float* __restrict__ lng, const float* __restrict__ lnb,
    float* __restrict__ out_h) {
    __shared__ float u_lds[ET][HID + 1];
    __shared__ float red[2][4][ET];

    const int tid = threadIdx.x;
    const int lane = tid & 63;
    const int wv = tid >> 6;
    const int o0 = wv << 5;   // divergent -> VMEM loads

    const int n = blockIdx.x * ET + lane;
    const bool valid = (n < NNODE);
    const int nc = valid ? n : (NNODE - 1);

    const float* __restrict__ hr = h + (size_t)nc * HID;
    const float* __restrict__ ar = agg_msg + (size_t)nc * HID;

    // ---- layer 1: silu([h, agg] @ Wn1 + bn1), K = 256 ----
    float acc[WO];
#pragma unroll
    for (int t = 0; t < WO; ++t) acc[t] = bn1[o0 + t];
#pragma unroll 2
    for (int kb = 0; kb < HID; kb += 4) {
        const float4 a = *reinterpret_cast<const float4*>(hr + kb);
        gemv4(acc, a.x, a.y, a.z, a.w, Wn1 + (size_t)kb * HID + o0);
    }
#pragma unroll 2
    for (int kb = 0; kb < HID; kb += 4) {
        const float4 a = *reinterpret_cast<const float4*>(ar + kb);
        gemv4(acc, a.x, a.y, a.z, a.w, Wn1 + (size_t)(HID + kb) * HID + o0);
    }
#pragma unroll
    for (int t = 0; t < WO; ++t) u_lds[lane][o0 + t] = silu_f(acc[t]);
    __syncthreads();

    // ---- layer 2: hn = u @ Wn2 + bn2, K = 128 ----
    float acc2[WO];
#pragma unroll
    for (int t = 0; t < WO; ++t) acc2[t] = bn2[o0 + t];
#pragma unroll 2
    for (int kb = 0; kb < HID; kb += 4) {
        const float a0 = u_lds[lane][kb + 0];
        const float a1 = u_lds[lane][kb + 1];
        const float a2 = u_lds[lane][kb + 2];
        const float a3 = u_lds[lane][kb + 3];
        gemv4(acc2, a0, a1, a2, a3, Wn2 + (size_t)kb * HID + o0);
    }

    // ---- FiLM + residual ----
    const int g = batch[nc];
    const float* __restrict__ fg = film + (size_t)g * 256;
    float x[WO];
    float s1 = 0.f;
#pragma unroll
    for (int t = 0; t < WO; ++t) {
        const float v = hr[o0 + t] + fmaf(fg[o0 + t], acc2[t], fg[128 + o0 + t]);
        x[t] = v;
        s1 += v;
    }
    red[0][wv][lane] = s1;
    __syncthreads();
    const float mu = (red[0][0][lane] + red[0][1][lane] +
                      red[0][2][lane] + red[0][3][lane]) * (1.f / 128.f);
    float s2 = 0.f;
#pragma unroll
    for (int t = 0; t < WO; ++t) {
        const float d = x[t] - mu;
        s2 += d * d;
    }
    red[1][wv][lane] = s2;
    __syncthreads();
    const float var = (red[1][0][lane] + red[1][1][lane] +
                       red[1][2][lane] + red[1][3][lane]) * (1.f / 128.f);
    const float rstd = 1.0f / sqrtf(var + 1e-5f);

    if (valid) {
        float* __restrict__ orow = out_h + (size_t)n * HID + o0;
#pragma unroll
        for (int t = 0; t < WO; ++t)
            orow[t] = (x[t] - mu) * rstd * lng[o0 + t] + lnb[o0 + t];
    }
}

// ---------------------------------------------------------------------------
extern "C" void kernel_launch(void* const* d_in, const int* in_sizes, int n_in,
                              void* d_out, int out_size, void* d_ws, size_t ws_size,
                              hipStream_t stream) {
    const float* h    = (const float*)d_in[0];
    const float* pos  = (const float*)d_in[1];
    const float* ea   = (const float*)d_in[2];
    const float* cond = (const float*)d_in[3];
    const int*   eidx = (const int*)d_in[4];
    const int*   batch= (const int*)d_in[5];
    const float* W1   = (const float*)d_in[6];
    const float* b1   = (const float*)d_in[7];
    const float* W2   = (const float*)d_in[8];
    const float* b2   = (const float*)d_in[9];
    const float* Wc1  = (const float*)d_in[10];
    const float* bc1  = (const float*)d_in[11];
    const float* Wc2  = (const float*)d_in[12];
    const float* Wn1  = (const float*)d_in[13];
    const float* bn1  = (const float*)d_in[14];
    const float* Wn2  = (const float*)d_in[15];
    const float* bn2  = (const float*)d_in[16];
    const float* Wf   = (const float*)d_in[17];
    const float* bf   = (const float*)d_in[18];
    const float* lng  = (const float*)d_in[19];
    const float* lnb  = (const float*)d_in[20];

    float* out_h   = (float*)d_out;                        // [N,128]
    float* out_pos = out_h + (size_t)NNODE * HID;          // [N,3]
    float* agg_msg = (float*)d_ws;                         // [N,128] scratch
    float* film    = agg_msg + (size_t)NNODE * HID;        // [64,256] scratch

    init_kernel<<<2048, 256, 0, stream>>>(pos, agg_msg, out_pos);
    film_kernel<<<NGRAPH, 256, 0, stream>>>(cond, Wf, bf, film);
    edge_kernel<<<NEDGE / ET, 256, 0, stream>>>(h, pos, ea, eidx,
                                                W1, b1, W2, b2, Wc1, bc1, Wc2,
                                                agg_msg, out_pos);
    node_kernel<<<(NNODE + ET - 1) / ET, 256, 0, stream>>>(h, agg_msg, film, batch,
                                                           Wn1, bn1, Wn2, bn2,
                                                           lng, lnb, out_h);
}

// Round 6
// 2129.164 us; speedup vs baseline: 42.3478x; 3.8030x over previous
//
#include <hip/hip_runtime.h>

#define HID 128
#define EPB 64         // edges (or nodes) per block
#define LDA 132        // padded LDS row stride (16B-aligned: 132*4 = 33*16)
#define NEDGE 800000
#define NNODE 50000
#define NGRAPH 64

__device__ __forceinline__ float silu_f(float x) {
    return x * __frcp_rn(1.0f + __expf(-x));
}

// GEMM chunk: acc[i][c] += sum_k A[e0+i][kb+k] * W[(kb+k)*HID + c0 + c]
// Weight loads: lanes cg=0..31 read 512B contiguous -> coalesced VMEM (L2-hot).
// A reads: 2 distinct addresses per wave (broadcast) -> conflict-free LDS.
template <int NKB>
__device__ __forceinline__ void gemm_block(float (&acc)[8][4],
                                           const float (*A)[LDA],
                                           const float* __restrict__ Wc,  // W + row0*HID + c0
                                           int e0) {
#pragma unroll 1
    for (int kb = 0; kb < NKB; kb += 4) {
        float4 w[4];
#pragma unroll
        for (int kk = 0; kk < 4; ++kk)
            w[kk] = *reinterpret_cast<const float4*>(Wc + (size_t)(kb + kk) * HID);
        float4 a[8];
#pragma unroll
        for (int i = 0; i < 8; ++i)
            a[i] = *reinterpret_cast<const float4*>(&A[e0 + i][kb]);
#pragma unroll
        for (int i = 0; i < 8; ++i) {
            const float aa[4] = {a[i].x, a[i].y, a[i].z, a[i].w};
#pragma unroll
            for (int kk = 0; kk < 4; ++kk) {
                acc[i][0] = fmaf(aa[kk], w[kk].x, acc[i][0]);
                acc[i][1] = fmaf(aa[kk], w[kk].y, acc[i][1]);
                acc[i][2] = fmaf(aa[kk], w[kk].z, acc[i][2]);
                acc[i][3] = fmaf(aa[kk], w[kk].w, acc[i][3]);
            }
        }
    }
}

// ---------------------------------------------------------------------------
// K0: zero agg_msg workspace, copy pos -> out_pos
// ---------------------------------------------------------------------------
__global__ __launch_bounds__(256) void init_kernel(const float* __restrict__ pos,
                                                   float* __restrict__ agg,
                                                   float* __restrict__ out_pos) {
    const int tid = blockIdx.x * blockDim.x + threadIdx.x;
    const int stride = gridDim.x * blockDim.x;
    float4* a4 = reinterpret_cast<float4*>(agg);
    const int nAgg4 = NNODE * HID / 4;
    for (int i = tid; i < nAgg4; i += stride) a4[i] = make_float4(0.f, 0.f, 0.f, 0.f);
    const float4* p4 = reinterpret_cast<const float4*>(pos);
    float4* o4 = reinterpret_cast<float4*>(out_pos);
    const int nPos4 = NNODE * 3 / 4;
    for (int i = tid; i < nPos4; i += stride) o4[i] = p4[i];
}

// ---------------------------------------------------------------------------
// K1: film = cond @ W_film + b_film   [64,128]@[128,256]
// ---------------------------------------------------------------------------
__global__ __launch_bounds__(256) void film_kernel(const float* __restrict__ cond,
                                                   const float* __restrict__ Wf,
                                                   const float* __restrict__ bf,
                                                   float* __restrict__ film) {
    const int g = blockIdx.x;
    const int o = threadIdx.x;
    const float* __restrict__ cg = cond + g * 128;
    float acc = bf[o];
    for (int k = 0; k < 128; ++k) acc = fmaf(cg[k], Wf[k * 256 + o], acc);
    film[g * 256 + o] = acc;
}

// ---------------------------------------------------------------------------
// K2: edge kernel. 256 threads: cg = tid&31 (col group, 4 cols), eg = tid>>5
// (edge group, 8 edges). acc[8][4] per thread.
// ---------------------------------------------------------------------------
__global__ __launch_bounds__(256) void edge_kernel(
    const float* __restrict__ h, const float* __restrict__ pos,
    const float* __restrict__ edge_attr, const int* __restrict__ eidx,
    const float* __restrict__ W1, const float* __restrict__ b1,
    const float* __restrict__ W2, const float* __restrict__ b2,
    const float* __restrict__ Wc1, const float* __restrict__ bc1,
    const float* __restrict__ Wc2,
    float* __restrict__ agg_msg, float* __restrict__ out_pos) {
    __shared__ float A[EPB][LDA];
    __shared__ float relx[EPB], rely[EPB], relz[EPB], d2s[EPB];
    __shared__ int ni_s[EPB];

    const int tid = threadIdx.x;
    const int cg = tid & 31;
    const int eg = tid >> 5;
    const int c0 = cg << 2;
    const int e0 = eg << 3;
    const int se = tid >> 2;     // staging: edge index 0..63
    const int q  = tid & 3;      // staging: quarter-row 0..3
    const int base = blockIdx.x * EPB;   // NEDGE % EPB == 0

    // ---- stage A = h_i rows; geometry ----
    {
        const int gi = eidx[base + se];
        if (q == 0) {
            const int gj = eidx[NEDGE + base + se];
            ni_s[se] = gi;
            const float ax = pos[gi*3+0], ay = pos[gi*3+1], az = pos[gi*3+2];
            const float bx = pos[gj*3+0], by = pos[gj*3+1], bz = pos[gj*3+2];
            const float rx = ax-bx, ry = ay-by, rz = az-bz;
            relx[se] = rx; rely[se] = ry; relz[se] = rz;
            d2s[se] = rx*rx + ry*ry + rz*rz;
        }
        const float* hrow = h + (size_t)gi * HID + q * 32;
#pragma unroll
        for (int j = 0; j < 8; ++j)
            *reinterpret_cast<float4*>(&A[se][q*32 + 4*j]) =
                *reinterpret_cast<const float4*>(hrow + 4*j);
    }
    __syncthreads();

    float acc[8][4];
    {
        const float4 b = *reinterpret_cast<const float4*>(b1 + c0);
#pragma unroll
        for (int i = 0; i < 8; ++i) {
            acc[i][0] = b.x; acc[i][1] = b.y; acc[i][2] = b.z; acc[i][3] = b.w;
        }
    }
    gemm_block<128>(acc, A, W1 + c0, e0);                       // k = 0..127 (h_i)
    __syncthreads();

    // ---- stage A = h_j rows ----
    {
        const int gj = eidx[NEDGE + base + se];
        const float* hrow = h + (size_t)gj * HID + q * 32;
#pragma unroll
        for (int j = 0; j < 8; ++j)
            *reinterpret_cast<float4*>(&A[se][q*32 + 4*j]) =
                *reinterpret_cast<const float4*>(hrow + 4*j);
    }
    __syncthreads();
    gemm_block<128>(acc, A, W1 + (size_t)128*HID + c0, e0);     // k = 128..255 (h_j)
    __syncthreads();

    // ---- stage A[:, 0..15] = edge_attr, A[:,16] = d2 ----
    if (q == 0) {
        const float* ear = edge_attr + (size_t)(base + se) * 16;
#pragma unroll
        for (int j = 0; j < 4; ++j)
            *reinterpret_cast<float4*>(&A[se][4*j]) =
                *reinterpret_cast<const float4*>(ear + 4*j);
        A[se][16] = d2s[se];
    }
    __syncthreads();
    gemm_block<16>(acc, A, W1 + (size_t)257*HID + c0, e0);      // edge_attr rows
    {
        const float4 wd = *reinterpret_cast<const float4*>(W1 + (size_t)256*HID + c0);
#pragma unroll
        for (int i = 0; i < 8; ++i) {
            const float dv = A[e0 + i][16];
            acc[i][0] = fmaf(dv, wd.x, acc[i][0]);
            acc[i][1] = fmaf(dv, wd.y, acc[i][1]);
            acc[i][2] = fmaf(dv, wd.z, acc[i][2]);
            acc[i][3] = fmaf(dv, wd.w, acc[i][3]);
        }
    }
    __syncthreads();   // tail reads of A complete before overwrite

    // ---- m = silu(L1) -> A; acc <- b2 ----
    {
        const float4 b = *reinterpret_cast<const float4*>(b2 + c0);
#pragma unroll
        for (int i = 0; i < 8; ++i) {
            float4 v;
            v.x = silu_f(acc[i][0]); v.y = silu_f(acc[i][1]);
            v.z = silu_f(acc[i][2]); v.w = silu_f(acc[i][3]);
            *reinterpret_cast<float4*>(&A[e0 + i][c0]) = v;
            acc[i][0] = b.x; acc[i][1] = b.y; acc[i][2] = b.z; acc[i][3] = b.w;
        }
    }
    __syncthreads();
    gemm_block<128>(acc, A, W2 + c0, e0);                       // layer 2
#pragma unroll
    for (int i = 0; i < 8; ++i) {
        acc[i][0] = silu_f(acc[i][0]); acc[i][1] = silu_f(acc[i][1]);
        acc[i][2] = silu_f(acc[i][2]); acc[i][3] = silu_f(acc[i][3]);
    }
    __syncthreads();   // layer-2 reads of A (m) complete

    // ---- m_ij -> A; scatter to agg_msg; acc <- bc1 ----
#pragma unroll
    for (int i = 0; i < 8; ++i) {
        float4 v; v.x = acc[i][0]; v.y = acc[i][1]; v.z = acc[i][2]; v.w = acc[i][3];
        *reinterpret_cast<float4*>(&A[e0 + i][c0]) = v;
    }
#pragma unroll
    for (int i = 0; i < 8; ++i) {
        float* am = agg_msg + (size_t)ni_s[e0 + i] * HID + c0;
        atomicAdd(am + 0, acc[i][0]);
        atomicAdd(am + 1, acc[i][1]);
        atomicAdd(am + 2, acc[i][2]);
        atomicAdd(am + 3, acc[i][3]);
    }
    {
        const float4 b = *reinterpret_cast<const float4*>(bc1 + c0);
#pragma unroll
        for (int i = 0; i < 8; ++i) {
            acc[i][0] = b.x; acc[i][1] = b.y; acc[i][2] = b.z; acc[i][3] = b.w;
        }
    }
    __syncthreads();
    gemm_block<128>(acc, A, Wc1 + c0, e0);                      // coord layer 1

    // ---- coord_w partials + half-wave butterfly reduce over cg ----
    const float4 w2v = *reinterpret_cast<const float4*>(Wc2 + c0);
    float p[8];
#pragma unroll
    for (int i = 0; i < 8; ++i)
        p[i] = silu_f(acc[i][0]) * w2v.x + silu_f(acc[i][1]) * w2v.y +
               silu_f(acc[i][2]) * w2v.z + silu_f(acc[i][3]) * w2v.w;
#pragma unroll
    for (int s = 16; s > 0; s >>= 1) {
#pragma unroll
        for (int i = 0; i < 8; ++i) p[i] += __shfl_xor(p[i], s, 32);
    }
    if (cg == 0) {
#pragma unroll
        for (int i = 0; i < 8; ++i) {
            const int e = e0 + i;
            const float sc = p[i] / sqrtf(d2s[e] + 1e-8f);
            float* op = out_pos + (size_t)ni_s[e] * 3;
            atomicAdd(op + 0, relx[e] * sc);
            atomicAdd(op + 1, rely[e] * sc);
            atomicAdd(op + 2, relz[e] * sc);
        }
    }
}

// ---------------------------------------------------------------------------
// K3: node kernel — node MLP + FiLM + residual + LayerNorm, same structure
// ---------------------------------------------------------------------------
__global__ __launch_bounds__(256) void node_kernel(
    const float* __restrict__ h, const float* __restrict__ agg_msg,
    const float* __restrict__ film, const int* __restrict__ batch,
    const float* __restrict__ Wn1, const float* __restrict__ bn1,
    const float* __restrict__ Wn2, const float* __restrict__ bn2,
    const float* __restrict__ lng, const float* __restrict__ lnb,
    float* __restrict__ out_h) {
    __shared__ float A[EPB][LDA];
    __shared__ int g_s[EPB];

    const int tid = threadIdx.x;
    const int cg = tid & 31;
    const int eg = tid >> 5;
    const int c0 = cg << 2;
    const int e0 = eg << 3;
    const int se = tid >> 2;
    const int q  = tid & 3;
    const int base = blockIdx.x * EPB;

    const int n_se = min(base + se, NNODE - 1);

    // ---- stage A = h rows ----
    {
        if (q == 0) g_s[se] = batch[n_se];
        const float* hrow = h + (size_t)n_se * HID + q * 32;
#pragma unroll
        for (int j = 0; j < 8; ++j)
            *reinterpret_cast<float4*>(&A[se][q*32 + 4*j]) =
                *reinterpret_cast<const float4*>(hrow + 4*j);
    }
    __syncthreads();

    float acc[8][4];
    {
        const float4 b = *reinterpret_cast<const float4*>(bn1 + c0);
#pragma unroll
        for (int i = 0; i < 8; ++i) {
            acc[i][0] = b.x; acc[i][1] = b.y; acc[i][2] = b.z; acc[i][3] = b.w;
        }
    }
    gemm_block<128>(acc, A, Wn1 + c0, e0);                      // k = 0..127 (h)
    __syncthreads();

    // ---- stage A = agg rows ----
    {
        const float* arow = agg_msg + (size_t)n_se * HID + q * 32;
#pragma unroll
        for (int j = 0; j < 8; ++j)
            *reinterpret_cast<float4*>(&A[se][q*32 + 4*j]) =
                *reinterpret_cast<const float4*>(arow + 4*j);
    }
    __syncthreads();
    gemm_block<128>(acc, A, Wn1 + (size_t)128*HID + c0, e0);    // k = 128..255 (agg)
    __syncthreads();

    // ---- u = silu -> A; acc <- bn2 ----
    {
        const float4 b = *reinterpret_cast<const float4*>(bn2 + c0);
#pragma unroll
        for (int i = 0; i < 8; ++i) {
            float4 v;
            v.x = silu_f(acc[i][0]); v.y = silu_f(acc[i][1]);
            v.z = silu_f(acc[i][2]); v.w = silu_f(acc[i][3]);
            *reinterpret_cast<float4*>(&A[e0 + i][c0]) = v;
            acc[i][0] = b.x; acc[i][1] = b.y; acc[i][2] = b.z; acc[i][3] = b.w;
        }
    }
    __syncthreads();
    gemm_block<128>(acc, A, Wn2 + c0, e0);                      // hn (pre-FiLM)

    // ---- FiLM + residual (in place into acc) ----
#pragma unroll
    for (int i = 0; i < 8; ++i) {
        const int nn = min(base + e0 + i, NNODE - 1);
        const int g = g_s[e0 + i];
        const float4 gm = *reinterpret_cast<const float4*>(film + (size_t)g*256 + c0);
        const float4 bt = *reinterpret_cast<const float4*>(film + (size_t)g*256 + 128 + c0);
        const float4 hv = *reinterpret_cast<const float4*>(h + (size_t)nn * HID + c0);
        acc[i][0] = hv.x + fmaf(gm.x, acc[i][0], bt.x);
        acc[i][1] = hv.y + fmaf(gm.y, acc[i][1], bt.y);
        acc[i][2] = hv.z + fmaf(gm.z, acc[i][2], bt.z);
        acc[i][3] = hv.w + fmaf(gm.w, acc[i][3], bt.w);
    }

    // ---- LayerNorm: butterfly over cg (32 col-groups = 128 cols) ----
    float p[8];
#pragma unroll
    for (int i = 0; i < 8; ++i) p[i] = acc[i][0] + acc[i][1] + acc[i][2] + acc[i][3];
#pragma unroll
    for (int s = 16; s > 0; s >>= 1) {
#pragma unroll
        for (int i = 0; i < 8; ++i) p[i] += __shfl_xor(p[i], s, 32);
    }
    float mu[8];
#pragma unroll
    for (int i = 0; i < 8; ++i) mu[i] = p[i] * (1.0f / 128.0f);
#pragma unroll
    for (int i = 0; i < 8; ++i) {
        const float d0 = acc[i][0] - mu[i], d1 = acc[i][1] - mu[i];
        const float d2 = acc[i][2] - mu[i], d3 = acc[i][3] - mu[i];
        p[i] = d0*d0 + d1*d1 + d2*d2 + d3*d3;
    }
#pragma unroll
    for (int s = 16; s > 0; s >>= 1) {
#pragma unroll
        for (int i = 0; i < 8; ++i) p[i] += __shfl_xor(p[i], s, 32);
    }

    const float4 gv = *reinterpret_cast<const float4*>(lng + c0);
    const float4 bv = *reinterpret_cast<const float4*>(lnb + c0);
#pragma unroll
    for (int i = 0; i < 8; ++i) {
        const int n = base + e0 + i;
        if (n < NNODE) {
            const float rstd = 1.0f / sqrtf(p[i] * (1.0f / 128.0f) + 1e-5f);
            float4 o;
            o.x = (acc[i][0] - mu[i]) * rstd * gv.x + bv.x;
            o.y = (acc[i][1] - mu[i]) * rstd * gv.y + bv.y;
            o.z = (acc[i][2] - mu[i]) * rstd * gv.z + bv.z;
            o.w = (acc[i][3] - mu[i]) * rstd * gv.w + bv.w;
            *reinterpret_cast<float4*>(out_h + (size_t)n * HID + c0) = o;
        }
    }
}

// ---------------------------------------------------------------------------
extern "C" void kernel_launch(void* const* d_in, const int* in_sizes, int n_in,
                              void* d_out, int out_size, void* d_ws, size_t ws_size,
                              hipStream_t stream) {
    const float* h    = (const float*)d_in[0];
    const float* pos  = (const float*)d_in[1];
    const float* ea   = (const float*)d_in[2];
    const float* cond = (const float*)d_in[3];
    const int*   eidx = (const int*)d_in[4];
    const int*   batch= (const int*)d_in[5];
    const float* W1   = (const float*)d_in[6];
    const float* b1   = (const float*)d_in[7];
    const float* W2   = (const float*)d_in[8];
    const float* b2   = (const float*)d_in[9];
    const float* Wc1  = (const float*)d_in[10];
    const float* bc1  = (const float*)d_in[11];
    const float* Wc2  = (const float*)d_in[12];
    const float* Wn1  = (const float*)d_in[13];
    const float* bn1  = (const float*)d_in[14];
    const float* Wn2  = (const float*)d_in[15];
    const float* bn2  = (const float*)d_in[16];
    const float* Wf   = (const float*)d_in[17];
    const float* bf   = (const float*)d_in[18];
    const float* lng  = (const float*)d_in[19];
    const float* lnb  = (const float*)d_in[20];

    float* out_h   = (float*)d_out;                        // [N,128]
    float* out_pos = out_h + (size_t)NNODE * HID;          // [N,3]
    float* agg_msg = (float*)d_ws;                         // [N,128] scratch
    float* film    = agg_msg + (size_t)NNODE * HID;        // [64,256] scratch

    init_kernel<<<2048, 256, 0, stream>>>(pos, agg_msg, out_pos);
    film_kernel<<<NGRAPH, 256, 0, stream>>>(cond, Wf, bf, film);
    edge_kernel<<<NEDGE / EPB, 256, 0, stream>>>(h, pos, ea, eidx,
                                                 W1, b1, W2, b2, Wc1, bc1, Wc2,
                                                 agg_msg, out_pos);
    node_kernel<<<(NNODE + EPB - 1) / EPB, 256, 0, stream>>>(h, agg_msg, film, batch,
                                                             Wn1, bn1, Wn2, bn2,
                                                             lng, lnb, out_h);
}

// Round 8
// 685.556 us; speedup vs baseline: 131.5216x; 3.1057x over previous
//
#include <hip/hip_runtime.h>

#define HID 128
#define NEDGE 800000
#define NNODE 50000
#define NGRAPH 64

typedef _Float16 f16;
typedef __attribute__((ext_vector_type(8))) _Float16 f16x8;
typedef __attribute__((ext_vector_type(4))) float f32x4;

__device__ __forceinline__ float silu_f(float x) {
    return x * __frcp_rn(1.0f + __expf(-x));
}

// 32 consecutive f32 -> f16 into LDS (dst 16B-aligned)
__device__ __forceinline__ void stage32(f16* dst, const float* __restrict__ src) {
#pragma unroll
    for (int i = 0; i < 4; ++i) {
        const float4 a = reinterpret_cast<const float4*>(src)[2 * i];
        const float4 b = reinterpret_cast<const float4*>(src)[2 * i + 1];
        f16x8 v;
        v[0] = (f16)a.x; v[1] = (f16)a.y; v[2] = (f16)a.z; v[3] = (f16)a.w;
        v[4] = (f16)b.x; v[5] = (f16)b.y; v[6] = (f16)b.z; v[7] = (f16)b.w;
        reinterpret_cast<f16x8*>(dst)[i] = v;
    }
}

// One K=32 MFMA step over 4 M-tiles x 2 N-tiles.
// A-frag: lane holds A[mt*16 + (lane&15)][kloc*32 + (lane>>4)*8 + 0..7]
// B-frag: packed so lane's 16B chunk is contiguous (see pack_kernel)
__device__ __forceinline__ void mfma_step(f32x4 (&acc)[4][2],
                                          const f16 (*A)[136], int kloc,
                                          const f16* __restrict__ Wp, int kt,
                                          int w, int lane) {
    const int r16 = lane & 15, g4 = lane >> 4;
    f16x8 bf[2];
#pragma unroll
    for (int nt = 0; nt < 2; ++nt)
        bf[nt] = *reinterpret_cast<const f16x8*>(
            Wp + (((size_t)kt * 8 + w * 2 + nt) * 64 + lane) * 8);
#pragma unroll
    for (int mt = 0; mt < 4; ++mt) {
        const f16x8 af = *reinterpret_cast<const f16x8*>(
            &A[mt * 16 + r16][kloc * 32 + g4 * 8]);
#pragma unroll
        for (int nt = 0; nt < 2; ++nt)
            acc[mt][nt] = __builtin_amdgcn_mfma_f32_16x16x32_f16(
                af, bf[nt], acc[mt][nt], 0, 0, 0);
    }
}

// ---------------------------------------------------------------------------
// K-pack: W [Kreal x 128] fp32 -> f16 B-fragments.
// chunk c: lane=c&63, nt=(c>>6)&7, kt=c>>9; element j:
//   out[c*8+j] = W[kt*32 + (lane>>4)*8 + j][nt*16 + (lane&15)]   (0 if k>=Kreal)
// ---------------------------------------------------------------------------
__global__ __launch_bounds__(256) void pack_kernel(const float* __restrict__ W,
                                                   f16* __restrict__ out,
                                                   int Kreal, int nchunks) {
    const int c = blockIdx.x * blockDim.x + threadIdx.x;
    if (c >= nchunks) return;
    const int l = c & 63;
    const int nt = (c >> 6) & 7;
    const int kt = c >> 9;
    const int col = nt * 16 + (l & 15);
    const int kbase = kt * 32 + ((l >> 4) << 3);
    f16x8 v;
#pragma unroll
    for (int j = 0; j < 8; ++j) {
        const int kr = kbase + j;
        v[j] = (kr < Kreal) ? (f16)W[(size_t)kr * HID + col] : (f16)0.f;
    }
    *reinterpret_cast<f16x8*>(out + (size_t)c * 8) = v;
}

// ---------------------------------------------------------------------------
// K0: zero agg_msg workspace, copy pos -> out_pos
// ---------------------------------------------------------------------------
__global__ __launch_bounds__(256) void init_kernel(const float* __restrict__ pos,
                                                   float* __restrict__ agg,
                                                   float* __restrict__ out_pos) {
    const int tid = blockIdx.x * blockDim.x + threadIdx.x;
    const int stride = gridDim.x * blockDim.x;
    float4* a4 = reinterpret_cast<float4*>(agg);
    const int nAgg4 = NNODE * HID / 4;
    for (int i = tid; i < nAgg4; i += stride) a4[i] = make_float4(0.f, 0.f, 0.f, 0.f);
    const float4* p4 = reinterpret_cast<const float4*>(pos);
    float4* o4 = reinterpret_cast<float4*>(out_pos);
    const int nPos4 = NNODE * 3 / 4;
    for (int i = tid; i < nPos4; i += stride) o4[i] = p4[i];
}

// ---------------------------------------------------------------------------
// K1: film = cond @ W_film + b_film  (fp32 exact, tiny)
// ---------------------------------------------------------------------------
__global__ __launch_bounds__(256) void film_kernel(const float* __restrict__ cond,
                                                   const float* __restrict__ Wf,
                                                   const float* __restrict__ bf,
                                                   float* __restrict__ film) {
    const int g = blockIdx.x;
    const int o = threadIdx.x;
    const float* __restrict__ cg = cond + g * 128;
    float acc = bf[o];
    for (int k = 0; k < 128; ++k) acc = fmaf(cg[k], Wf[k * 256 + o], acc);
    film[g * 256 + o] = acc;
}

// ---------------------------------------------------------------------------
// K2: edge kernel — MFMA GEMMs (f16 in, f32 acc), fp32 everything else.
// Block = 64 edges x 128 cols; wave w owns cols [w*32, w*32+32).
// ---------------------------------------------------------------------------
__global__ __launch_bounds__(256) void edge_kernel(
    const float* __restrict__ h, const float* __restrict__ pos,
    const float* __restrict__ edge_attr, const int* __restrict__ eidx,
    const f16* __restrict__ W1p, const float* __restrict__ b1,
    const f16* __restrict__ W2p, const float* __restrict__ b2,
    const f16* __restrict__ Wc1p, const float* __restrict__ bc1,
    const float* __restrict__ Wc2,
    float* __restrict__ agg_msg, float* __restrict__ out_pos) {
    __shared__ f16 Asm[64][136];
    __shared__ float relx[64], rely[64], relz[64], d2s[64];
    __shared__ int ni_s[64];
    __shared__ float cw_part[4][64];

    const int tid = threadIdx.x;
    const int lane = tid & 63;
    const int w = tid >> 6;
    const int r16 = lane & 15;
    const int g4 = lane >> 4;
    const int se = tid >> 2, q = tid & 3;
    const int base = blockIdx.x * 64;          // NEDGE % 64 == 0

    // ---- stage h_i + geometry ----
    {
        const int gi = eidx[base + se];
        if (q == 0) {
            const int gj = eidx[NEDGE + base + se];
            ni_s[se] = gi;
            const float ax = pos[gi*3+0], ay = pos[gi*3+1], az = pos[gi*3+2];
            const float bx = pos[gj*3+0], by = pos[gj*3+1], bz = pos[gj*3+2];
            const float rx = ax-bx, ry = ay-by, rz = az-bz;
            relx[se] = rx; rely[se] = ry; relz[se] = rz;
            d2s[se] = rx*rx + ry*ry + rz*rz;
        }
        stage32(&Asm[se][q * 32], h + (size_t)eidx[base + se] * HID + q * 32);
    }
    __syncthreads();

    // ---- layer 1 ----
    f32x4 acc[4][2];
#pragma unroll
    for (int nt = 0; nt < 2; ++nt) {
        const float b = b1[w * 32 + nt * 16 + r16];
#pragma unroll
        for (int mt = 0; mt < 4; ++mt) acc[mt][nt] = (f32x4){b, b, b, b};
    }
#pragma unroll
    for (int kt = 0; kt < 4; ++kt) mfma_step(acc, Asm, kt, W1p, kt, w, lane);
    __syncthreads();

    {   // stage h_j
        const int gj = eidx[NEDGE + base + se];
        stage32(&Asm[se][q * 32], h + (size_t)gj * HID + q * 32);
    }
    __syncthreads();
#pragma unroll
    for (int kt = 0; kt < 4; ++kt) mfma_step(acc, Asm, kt, W1p, 4 + kt, w, lane);
    __syncthreads();

    {   // tail: A[:,0]=d2, A[:,1..16]=edge_attr, A[:,17..31]=0
        f16x8 v;
#pragma unroll
        for (int j = 0; j < 8; ++j) {
            const int c = q * 8 + j;
            float val = 0.f;
            if (c == 0) val = d2s[se];
            else if (c <= 16) val = edge_attr[(size_t)(base + se) * 16 + (c - 1)];
            v[j] = (f16)val;
        }
        reinterpret_cast<f16x8*>(&Asm[se][0])[q] = v;
    }
    __syncthreads();
    mfma_step(acc, Asm, 0, W1p, 8, w, lane);
    __syncthreads();   // tail reads done before m overwrite

    // ---- m = silu(L1) -> Asm (f16) ----
#pragma unroll
    for (int mt = 0; mt < 4; ++mt)
#pragma unroll
        for (int nt = 0; nt < 2; ++nt)
#pragma unroll
            for (int r = 0; r < 4; ++r)
                Asm[mt*16 + g4*4 + r][w*32 + nt*16 + r16] = (f16)silu_f(acc[mt][nt][r]);
    __syncthreads();

    // ---- layer 2 ----
    f32x4 acc2[4][2];
#pragma unroll
    for (int nt = 0; nt < 2; ++nt) {
        const float b = b2[w * 32 + nt * 16 + r16];
#pragma unroll
        for (int mt = 0; mt < 4; ++mt) acc2[mt][nt] = (f32x4){b, b, b, b};
    }
#pragma unroll
    for (int kt = 0; kt < 4; ++kt) mfma_step(acc2, Asm, kt, W2p, kt, w, lane);
    __syncthreads();   // L2 reads done before m_ij overwrite

    // ---- m_ij = silu(L2): write Asm (f16) + fp32 atomic scatter ----
#pragma unroll
    for (int mt = 0; mt < 4; ++mt)
#pragma unroll
        for (int r = 0; r < 4; ++r) {
            const int e = mt*16 + g4*4 + r;
            float* am = agg_msg + (size_t)ni_s[e] * HID + w*32 + r16;
#pragma unroll
            for (int nt = 0; nt < 2; ++nt) {
                const float v = silu_f(acc2[mt][nt][r]);
                Asm[e][w*32 + nt*16 + r16] = (f16)v;
                atomicAdd(am + nt*16, v);
            }
        }
    __syncthreads();

    // ---- coord layer ----
    f32x4 acc3[4][2];
#pragma unroll
    for (int nt = 0; nt < 2; ++nt) {
        const float b = bc1[w * 32 + nt * 16 + r16];
#pragma unroll
        for (int mt = 0; mt < 4; ++mt) acc3[mt][nt] = (f32x4){b, b, b, b};
    }
#pragma unroll
    for (int kt = 0; kt < 4; ++kt) mfma_step(acc3, Asm, kt, Wc1p, kt, w, lane);

    const float wc0 = Wc2[w*32 + r16], wc1 = Wc2[w*32 + 16 + r16];
#pragma unroll
    for (int mt = 0; mt < 4; ++mt)
#pragma unroll
        for (int r = 0; r < 4; ++r) {
            float p = silu_f(acc3[mt][0][r]) * wc0 + silu_f(acc3[mt][1][r]) * wc1;
#pragma unroll
            for (int s = 1; s < 16; s <<= 1) p += __shfl_xor(p, s, 16);
            if (r16 == 0) cw_part[w][mt*16 + g4*4 + r] = p;
        }
    __syncthreads();

    if (tid < 64) {
        const int e = tid;
        const float cwf = cw_part[0][e] + cw_part[1][e] + cw_part[2][e] + cw_part[3][e];
        const float sc = cwf / sqrtf(d2s[e] + 1e-8f);
        float* op = out_pos + (size_t)ni_s[e] * 3;
        atomicAdd(op + 0, relx[e] * sc);
        atomicAdd(op + 1, rely[e] * sc);
        atomicAdd(op + 2, relz[e] * sc);
    }
}

// ---------------------------------------------------------------------------
// K3: node kernel — MFMA node MLP + FiLM + residual + LayerNorm
// ---------------------------------------------------------------------------
__global__ __launch_bounds__(256) void node_kernel(
    const float* __restrict__ h, const float* __restrict__ agg_msg,
    const float* __restrict__ film, const int* __restrict__ batch,
    const f16* __restrict__ Wn1p, const float* __restrict__ bn1,
    const f16* __restrict__ Wn2p, const float* __restrict__ bn2,
    const float* __restrict__ lng, const float* __restrict__ lnb,
    float* __restrict__ out_h) {
    __shared__ f16 Asm[64][136];
    __shared__ int g_s[64];
    __shared__ float red[4][64];
    __shared__ float mu_s[64], rs_s[64];

    const int tid = threadIdx.x;
    const int lane = tid & 63;
    const int w = tid >> 6;
    const int r16 = lane & 15;
    const int g4 = lane >> 4;
    const int se = tid >> 2, q = tid & 3;
    const int base = blockIdx.x * 64;

    const int n_se = min(base + se, NNODE - 1);
    if (q == 0) g_s[se] = batch[n_se];
    stage32(&Asm[se][q * 32], h + (size_t)n_se * HID + q * 32);
    __syncthreads();

    f32x4 acc[4][2];
#pragma unroll
    for (int nt = 0; nt < 2; ++nt) {
        const float b = bn1[w * 32 + nt * 16 + r16];
#pragma unroll
        for (int mt = 0; mt < 4; ++mt) acc[mt][nt] = (f32x4){b, b, b, b};
    }
#pragma unroll
    for (int kt = 0; kt < 4; ++kt) mfma_step(acc, Asm, kt, Wn1p, kt, w, lane);
    __syncthreads();

    stage32(&Asm[se][q * 32], agg_msg + (size_t)n_se * HID + q * 32);
    __syncthreads();
#pragma unroll
    for (int kt = 0; kt < 4; ++kt) mfma_step(acc, Asm, kt, Wn1p, 4 + kt, w, lane);
    __syncthreads();

    // u = silu -> Asm
#pragma unroll
    for (int mt = 0; mt < 4; ++mt)
#pragma unroll
        for (int nt = 0; nt < 2; ++nt)
#pragma unroll
            for (int r = 0; r < 4; ++r)
                Asm[mt*16 + g4*4 + r][w*32 + nt*16 + r16] = (f16)silu_f(acc[mt][nt][r]);
    __syncthreads();

    f32x4 acc2[4][2];
#pragma unroll
    for (int nt = 0; nt < 2; ++nt) {
        const float b = bn2[w * 32 + nt * 16 + r16];
#pragma unroll
        for (int mt = 0; mt < 4; ++mt) acc2[mt][nt] = (f32x4){b, b, b, b};
    }
#pragma unroll
    for (int kt = 0; kt < 4; ++kt) mfma_step(acc2, Asm, kt, Wn2p, kt, w, lane);

    // ---- FiLM + residual (x kept in acc2, fp32) ----
#pragma unroll
    for (int mt = 0; mt < 4; ++mt)
#pragma unroll
        for (int r = 0; r < 4; ++r) {
            const int erow = mt*16 + g4*4 + r;
            const int nc = min(base + erow, NNODE - 1);
            const int g = g_s[erow];
#pragma unroll
            for (int nt = 0; nt < 2; ++nt) {
                const int col = w*32 + nt*16 + r16;
                const float gm = film[(size_t)g*256 + col];
                const float bt = film[(size_t)g*256 + 128 + col];
                const float hv = h[(size_t)nc * HID + col];
                acc2[mt][nt][r] = hv + fmaf(gm, acc2[mt][nt][r], bt);
            }
        }

    // ---- LayerNorm: mean ----
#pragma unroll
    for (int mt = 0; mt < 4; ++mt)
#pragma unroll
        for (int r = 0; r < 4; ++r) {
            float p = acc2[mt][0][r] + acc2[mt][1][r];
#pragma unroll
            for (int s = 1; s < 16; s <<= 1) p += __shfl_xor(p, s, 16);
            if (r16 == 0) red[w][mt*16 + g4*4 + r] = p;
        }
    __syncthreads();
    if (tid < 64) mu_s[tid] = (red[0][tid] + red[1][tid] + red[2][tid] + red[3][tid]) * (1.f / 128.f);
    __syncthreads();

    // ---- variance ----
#pragma unroll
    for (int mt = 0; mt < 4; ++mt)
#pragma unroll
        for (int r = 0; r < 4; ++r) {
            const float m = mu_s[mt*16 + g4*4 + r];
            const float d0 = acc2[mt][0][r] - m, d1 = acc2[mt][1][r] - m;
            float p = d0*d0 + d1*d1;
#pragma unroll
            for (int s = 1; s < 16; s <<= 1) p += __shfl_xor(p, s, 16);
            if (r16 == 0) red[w][mt*16 + g4*4 + r] = p;
        }
    __syncthreads();
    if (tid < 64) {
        const float var = (red[0][tid] + red[1][tid] + red[2][tid] + red[3][tid]) * (1.f / 128.f);
        rs_s[tid] = 1.0f / sqrtf(var + 1e-5f);
    }
    __syncthreads();

    // ---- write ----
    const float lg0 = lng[w*32 + r16], lb0 = lnb[w*32 + r16];
    const float lg1 = lng[w*32 + 16 + r16], lb1 = lnb[w*32 + 16 + r16];
#pragma unroll
    for (int mt = 0; mt < 4; ++mt)
#pragma unroll
        for (int r = 0; r < 4; ++r) {
            const int erow = mt*16 + g4*4 + r;
            const int n = base + erow;
            if (n < NNODE) {
                const float m = mu_s[erow], rs = rs_s[erow];
                out_h[(size_t)n * HID + w*32 + r16]      = (acc2[mt][0][r] - m) * rs * lg0 + lb0;
                out_h[(size_t)n * HID + w*32 + 16 + r16] = (acc2[mt][1][r] - m) * rs * lg1 + lb1;
            }
        }
}

// ---------------------------------------------------------------------------
extern "C" void kernel_launch(void* const* d_in, const int* in_sizes, int n_in,
                              void* d_out, int out_size, void* d_ws, size_t ws_size,
                              hipStream_t stream) {
    const float* h    = (const float*)d_in[0];
    const float* pos  = (const float*)d_in[1];
    const float* ea   = (const float*)d_in[2];
    const float* cond = (const float*)d_in[3];
    const int*   eidx = (const int*)d_in[4];
    const int*   batch= (const int*)d_in[5];
    const float* W1   = (const float*)d_in[6];
    const float* b1   = (const float*)d_in[7];
    const float* W2   = (const float*)d_in[8];
    const float* b2   = (const float*)d_in[9];
    const float* Wc1  = (const float*)d_in[10];
    const float* bc1  = (const float*)d_in[11];
    const float* Wc2  = (const float*)d_in[12];
    const float* Wn1  = (const float*)d_in[13];
    const float* bn1  = (const float*)d_in[14];
    const float* Wn2  = (const float*)d_in[15];
    const float* bn2  = (const float*)d_in[16];
    const float* Wf   = (const float*)d_in[17];
    const float* bf   = (const float*)d_in[18];
    const float* lng  = (const float*)d_in[19];
    const float* lnb  = (const float*)d_in[20];

    float* out_h   = (float*)d_out;                        // [N,128]
    float* out_pos = out_h + (size_t)NNODE * HID;          // [N,3]
    float* agg_msg = (float*)d_ws;                         // [N,128]  25.6 MB
    float* film    = agg_msg + (size_t)NNODE * HID;        // [64,256] 64 KB
    f16*   W1p     = (f16*)(film + 64 * 256);              // packed f16 weights
    f16*   W2p     = W1p  + (size_t)4608 * 8;              // W1: 9 ktiles
    f16*   Wc1p    = W2p  + (size_t)2048 * 8;              // W2: 4 ktiles
    f16*   Wn1p    = Wc1p + (size_t)2048 * 8;              // Wc1: 4 ktiles
    f16*   Wn2p    = Wn1p + (size_t)4096 * 8;              // Wn1: 8 ktiles

    init_kernel<<<2048, 256, 0, stream>>>(pos, agg_msg, out_pos);
    film_kernel<<<NGRAPH, 256, 0, stream>>>(cond, Wf, bf, film);
    pack_kernel<<<18, 256, 0, stream>>>(W1,  W1p,  273, 4608);
    pack_kernel<<<8,  256, 0, stream>>>(W2,  W2p,  128, 2048);
    pack_kernel<<<8,  256, 0, stream>>>(Wc1, Wc1p, 128, 2048);
    pack_kernel<<<16, 256, 0, stream>>>(Wn1, Wn1p, 256, 4096);
    pack_kernel<<<8,  256, 0, stream>>>(Wn2, Wn2p, 128, 2048);
    edge_kernel<<<NEDGE / 64, 256, 0, stream>>>(h, pos, ea, eidx,
                                                W1p, b1, W2p, b2, Wc1p, bc1, Wc2,
                                                agg_msg, out_pos);
    node_kernel<<<(NNODE + 63) / 64, 256, 0, stream>>>(h, agg_msg, film, batch,
                                                       Wn1p, bn1, Wn2p, bn2,
                                                       lng, lnb, out_h);
}

// Round 9
// 674.033 us; speedup vs baseline: 133.7702x; 1.0171x over previous
//
#include <hip/hip_runtime.h>

#define HID 128
#define NEDGE 800000
#define NNODE 50000
#define NGRAPH 64

typedef _Float16 f16;
typedef __attribute__((ext_vector_type(8))) _Float16 f16x8;
typedef __attribute__((ext_vector_type(4))) float f32x4;

__device__ __forceinline__ float silu_f(float x) {
    return x * __frcp_rn(1.0f + __expf(-x));
}

// 32 consecutive f32 -> f16 into LDS (dst 16B-aligned)
__device__ __forceinline__ void stage32(f16* dst, const float* __restrict__ src) {
#pragma unroll
    for (int i = 0; i < 4; ++i) {
        const float4 a = reinterpret_cast<const float4*>(src)[2 * i];
        const float4 b = reinterpret_cast<const float4*>(src)[2 * i + 1];
        f16x8 v;
        v[0] = (f16)a.x; v[1] = (f16)a.y; v[2] = (f16)a.z; v[3] = (f16)a.w;
        v[4] = (f16)b.x; v[5] = (f16)b.y; v[6] = (f16)b.z; v[7] = (f16)b.w;
        reinterpret_cast<f16x8*>(dst)[i] = v;
    }
}

// One K=32 MFMA step over 4 M-tiles x 2 N-tiles (proven r8 core).
// A-frag: lane holds A[mt*16 + (lane&15)][kloc*32 + (lane>>4)*8 + 0..7]
// B-frag: packed contiguous per lane (see pack in prep_kernel)
template <int LD>
__device__ __forceinline__ void mfma_step(f32x4 (&acc)[4][2],
                                          const f16 (*A)[LD], int kloc,
                                          const f16* __restrict__ Wp, int kt,
                                          int w, int lane) {
    const int r16 = lane & 15, g4 = lane >> 4;
    f16x8 bf[2];
#pragma unroll
    for (int nt = 0; nt < 2; ++nt)
        bf[nt] = *reinterpret_cast<const f16x8*>(
            Wp + (((size_t)kt * 8 + w * 2 + nt) * 64 + lane) * 8);
#pragma unroll
    for (int mt = 0; mt < 4; ++mt) {
        const f16x8 af = *reinterpret_cast<const f16x8*>(
            &A[mt * 16 + r16][kloc * 32 + g4 * 8]);
#pragma unroll
        for (int nt = 0; nt < 2; ++nt)
            acc[mt][nt] = __builtin_amdgcn_mfma_f32_16x16x32_f16(
                af, bf[nt], acc[mt][nt], 0, 0, 0);
    }
}

// ---------------------------------------------------------------------------
// prep: fused {film | weight packs | agg zero + pos copy} partitioned by block
// blocks [0,64): film;  [64,128): packs;  [128,1792): init
// ---------------------------------------------------------------------------
__global__ __launch_bounds__(256) void prep_kernel(
    const float* __restrict__ pos, float* __restrict__ agg,
    float* __restrict__ out_pos,
    const float* __restrict__ cond, const float* __restrict__ Wf,
    const float* __restrict__ bfb, float* __restrict__ film,
    const float* __restrict__ W1, const float* __restrict__ W2,
    const float* __restrict__ Wc1, const float* __restrict__ Wn1,
    const float* __restrict__ Wn2,
    f16* __restrict__ W1p, f16* __restrict__ W2p, f16* __restrict__ Wc1p,
    f16* __restrict__ Wn1p, f16* __restrict__ Wn2p) {
    const int b = blockIdx.x;
    const int t = threadIdx.x;
    if (b < 64) {                      // ---- film (fp32 exact) ----
        const float* __restrict__ cg = cond + b * 128;
        float acc = bfb[t];
        for (int k = 0; k < 128; ++k) acc = fmaf(cg[k], Wf[k * 256 + t], acc);
        film[b * 256 + t] = acc;
        return;
    }
    if (b < 128) {                     // ---- weight packs ----
        const int pb = b - 64;
        const float* W; f16* outp; int Kreal, nchunks, cb;
        if (pb < 18)      { W = W1;  outp = W1p;  Kreal = 273; nchunks = 4608; cb = pb; }
        else if (pb < 26) { W = W2;  outp = W2p;  Kreal = 128; nchunks = 2048; cb = pb - 18; }
        else if (pb < 34) { W = Wc1; outp = Wc1p; Kreal = 128; nchunks = 2048; cb = pb - 26; }
        else if (pb < 50) { W = Wn1; outp = Wn1p; Kreal = 256; nchunks = 4096; cb = pb - 34; }
        else if (pb < 58) { W = Wn2; outp = Wn2p; Kreal = 128; nchunks = 2048; cb = pb - 50; }
        else return;
        const int c = cb * 256 + t;
        if (c >= nchunks) return;
        const int l = c & 63;
        const int nt = (c >> 6) & 7;
        const int kt = c >> 9;
        const int col = nt * 16 + (l & 15);
        const int kbase = kt * 32 + ((l >> 4) << 3);
        f16x8 v;
#pragma unroll
        for (int j = 0; j < 8; ++j) {
            const int kr = kbase + j;
            v[j] = (kr < Kreal) ? (f16)W[(size_t)kr * HID + col] : (f16)0.f;
        }
        *reinterpret_cast<f16x8*>(outp + (size_t)c * 8) = v;
        return;
    }
    // ---- init: zero agg, copy pos -> out_pos ----
    const int tid = (b - 128) * 256 + t;
    const int stride = (gridDim.x - 128) * 256;
    float4* a4 = reinterpret_cast<float4*>(agg);
    const int nAgg4 = NNODE * HID / 4;
    for (int i = tid; i < nAgg4; i += stride) a4[i] = make_float4(0.f, 0.f, 0.f, 0.f);
    const float4* p4 = reinterpret_cast<const float4*>(pos);
    float4* o4 = reinterpret_cast<float4*>(out_pos);
    const int nPos4 = NNODE * 3 / 4;
    for (int i = tid; i < nPos4; i += stride) o4[i] = p4[i];
}

// ---------------------------------------------------------------------------
// edge kernel — all staging upfront (concurrent gathers), 5 barriers total.
// Block = 64 edges x 128 cols; wave w owns cols [w*32, w*32+32).
// ---------------------------------------------------------------------------
__global__ __launch_bounds__(256) void edge_kernel(
    const float* __restrict__ h, const float* __restrict__ pos,
    const float* __restrict__ edge_attr, const int* __restrict__ eidx,
    const f16* __restrict__ W1p, const float* __restrict__ b1,
    const f16* __restrict__ W2p, const float* __restrict__ b2,
    const f16* __restrict__ Wc1p, const float* __restrict__ bc1,
    const float* __restrict__ Wc2,
    float* __restrict__ agg_msg, float* __restrict__ out_pos) {
    __shared__ f16 Ahi[64][136];      // h_i; later m
    __shared__ f16 Ahj[64][136];      // h_j; later m_ij
    __shared__ f16 Atl[64][40];       // tail: d2 | edge_attr | 0-pad
    __shared__ float relx[64], rely[64], relz[64], d2s[64];
    __shared__ int ni_s[64];
    __shared__ float cw_part[4][64];

    const int tid = threadIdx.x;
    const int lane = tid & 63;
    const int w = tid >> 6;
    const int r16 = lane & 15;
    const int g4 = lane >> 4;
    const int se = tid >> 2, q = tid & 3;
    const int base = blockIdx.x * 64;          // NEDGE % 64 == 0

    // ---- stage EVERYTHING upfront: h_i, h_j, tail (loads overlap) ----
    const int gi = eidx[base + se];
    const int gj = eidx[NEDGE + base + se];
    float d2loc = 0.f;
    if (q == 0) {
        ni_s[se] = gi;
        const float ax = pos[gi*3+0], ay = pos[gi*3+1], az = pos[gi*3+2];
        const float bx = pos[gj*3+0], by = pos[gj*3+1], bz = pos[gj*3+2];
        const float rx = ax-bx, ry = ay-by, rz = az-bz;
        relx[se] = rx; rely[se] = ry; relz[se] = rz;
        d2loc = rx*rx + ry*ry + rz*rz;
        d2s[se] = d2loc;
    }
    stage32(&Ahi[se][q * 32], h + (size_t)gi * HID + q * 32);
    stage32(&Ahj[se][q * 32], h + (size_t)gj * HID + q * 32);
    {   // tail cols q*8..q*8+7:  col0 = d2 (q==0 local), 1..16 = edge_attr, else 0
        f16x8 v;
#pragma unroll
        for (int j = 0; j < 8; ++j) {
            const int c = q * 8 + j;
            float val = 0.f;
            if (c == 0) val = d2loc;
            else if (c <= 16) val = edge_attr[(size_t)(base + se) * 16 + (c - 1)];
            v[j] = (f16)val;
        }
        *reinterpret_cast<f16x8*>(&Atl[se][q * 8]) = v;
    }
    __syncthreads();                                        // B1

    // ---- layer 1: 9 K-tiles straight through ----
    f32x4 acc[4][2];
#pragma unroll
    for (int nt = 0; nt < 2; ++nt) {
        const float b = b1[w * 32 + nt * 16 + r16];
#pragma unroll
        for (int mt = 0; mt < 4; ++mt) acc[mt][nt] = (f32x4){b, b, b, b};
    }
#pragma unroll
    for (int kt = 0; kt < 4; ++kt) mfma_step<136>(acc, Ahi, kt, W1p, kt, w, lane);
#pragma unroll
    for (int kt = 0; kt < 4; ++kt) mfma_step<136>(acc, Ahj, kt, W1p, 4 + kt, w, lane);
    mfma_step<40>(acc, Atl, 0, W1p, 8, w, lane);
    __syncthreads();                                        // B2 (all L1 reads done)

    // ---- m = silu(L1) -> Ahi (C-layout) ----
#pragma unroll
    for (int mt = 0; mt < 4; ++mt)
#pragma unroll
        for (int nt = 0; nt < 2; ++nt)
#pragma unroll
            for (int r = 0; r < 4; ++r)
                Ahi[mt*16 + g4*4 + r][w*32 + nt*16 + r16] = (f16)silu_f(acc[mt][nt][r]);
    __syncthreads();                                        // B3

    // ---- layer 2 (reads Ahi = m) ----
    f32x4 acc2[4][2];
#pragma unroll
    for (int nt = 0; nt < 2; ++nt) {
        const float b = b2[w * 32 + nt * 16 + r16];
#pragma unroll
        for (int mt = 0; mt < 4; ++mt) acc2[mt][nt] = (f32x4){b, b, b, b};
    }
#pragma unroll
    for (int kt = 0; kt < 4; ++kt) mfma_step<136>(acc2, Ahi, kt, W2p, kt, w, lane);

    // ---- m_ij = silu(L2) -> Ahj (no barrier needed: Ahj idle) + atomic scatter ----
#pragma unroll
    for (int mt = 0; mt < 4; ++mt)
#pragma unroll
        for (int r = 0; r < 4; ++r) {
            const int e = mt*16 + g4*4 + r;
            float* am = agg_msg + (size_t)ni_s[e] * HID + w*32 + r16;
#pragma unroll
            for (int nt = 0; nt < 2; ++nt) {
                const float v = silu_f(acc2[mt][nt][r]);
                Ahj[e][w*32 + nt*16 + r16] = (f16)v;
                atomicAdd(am + nt*16, v);
            }
        }
    __syncthreads();                                        // B4

    // ---- coord layer (reads Ahj = m_ij) ----
    f32x4 acc3[4][2];
#pragma unroll
    for (int nt = 0; nt < 2; ++nt) {
        const float b = bc1[w * 32 + nt * 16 + r16];
#pragma unroll
        for (int mt = 0; mt < 4; ++mt) acc3[mt][nt] = (f32x4){b, b, b, b};
    }
#pragma unroll
    for (int kt = 0; kt < 4; ++kt) mfma_step<136>(acc3, Ahj, kt, Wc1p, kt, w, lane);

    const float wc0 = Wc2[w*32 + r16], wc1 = Wc2[w*32 + 16 + r16];
#pragma unroll
    for (int mt = 0; mt < 4; ++mt)
#pragma unroll
        for (int r = 0; r < 4; ++r) {
            float p = silu_f(acc3[mt][0][r]) * wc0 + silu_f(acc3[mt][1][r]) * wc1;
#pragma unroll
            for (int s = 1; s < 16; s <<= 1) p += __shfl_xor(p, s, 16);
            if (r16 == 0) cw_part[w][mt*16 + g4*4 + r] = p;
        }
    __syncthreads();                                        // B5

    if (tid < 64) {
        const int e = tid;
        const float cwf = cw_part[0][e] + cw_part[1][e] + cw_part[2][e] + cw_part[3][e];
        const float sc = cwf / sqrtf(d2s[e] + 1e-8f);
        float* op = out_pos + (size_t)ni_s[e] * 3;
        atomicAdd(op + 0, relx[e] * sc);
        atomicAdd(op + 1, rely[e] * sc);
        atomicAdd(op + 2, relz[e] * sc);
    }
}

// ---------------------------------------------------------------------------
// node kernel — upfront staging of h + agg, then MLP + FiLM + LayerNorm
// ---------------------------------------------------------------------------
__global__ __launch_bounds__(256) void node_kernel(
    const float* __restrict__ h, const float* __restrict__ agg_msg,
    const float* __restrict__ film, const int* __restrict__ batch,
    const f16* __restrict__ Wn1p, const float* __restrict__ bn1,
    const f16* __restrict__ Wn2p, const float* __restrict__ bn2,
    const float* __restrict__ lng, const float* __restrict__ lnb,
    float* __restrict__ out_h) {
    __shared__ f16 A1[64][136];     // h; later u
    __shared__ f16 A2[64][136];     // agg
    __shared__ int g_s[64];
    __shared__ float red[4][64];
    __shared__ float mu_s[64], rs_s[64];

    const int tid = threadIdx.x;
    const int lane = tid & 63;
    const int w = tid >> 6;
    const int r16 = lane & 15;
    const int g4 = lane >> 4;
    const int se = tid >> 2, q = tid & 3;
    const int base = blockIdx.x * 64;

    const int n_se = min(base + se, NNODE - 1);
    if (q == 0) g_s[se] = batch[n_se];
    stage32(&A1[se][q * 32], h + (size_t)n_se * HID + q * 32);
    stage32(&A2[se][q * 32], agg_msg + (size_t)n_se * HID + q * 32);
    __syncthreads();

    f32x4 acc[4][2];
#pragma unroll
    for (int nt = 0; nt < 2; ++nt) {
        const float b = bn1[w * 32 + nt * 16 + r16];
#pragma unroll
        for (int mt = 0; mt < 4; ++mt) acc[mt][nt] = (f32x4){b, b, b, b};
    }
#pragma unroll
    for (int kt = 0; kt < 4; ++kt) mfma_step<136>(acc, A1, kt, Wn1p, kt, w, lane);
#pragma unroll
    for (int kt = 0; kt < 4; ++kt) mfma_step<136>(acc, A2, kt, Wn1p, 4 + kt, w, lane);
    __syncthreads();

    // u = silu -> A1
#pragma unroll
    for (int mt = 0; mt < 4; ++mt)
#pragma unroll
        for (int nt = 0; nt < 2; ++nt)
#pragma unroll
            for (int r = 0; r < 4; ++r)
                A1[mt*16 + g4*4 + r][w*32 + nt*16 + r16] = (f16)silu_f(acc[mt][nt][r]);
    __syncthreads();

    f32x4 acc2[4][2];
#pragma unroll
    for (int nt = 0; nt < 2; ++nt) {
        const float b = bn2[w * 32 + nt * 16 + r16];
#pragma unroll
        for (int mt = 0; mt < 4; ++mt) acc2[mt][nt] = (f32x4){b, b, b, b};
    }
#pragma unroll
    for (int kt = 0; kt < 4; ++kt) mfma_step<136>(acc2, A1, kt, Wn2p, kt, w, lane);

    // ---- FiLM + residual ----
#pragma unroll
    for (int mt = 0; mt < 4; ++mt)
#pragma unroll
        for (int r = 0; r < 4; ++r) {
            const int erow = mt*16 + g4*4 + r;
            const int nc = min(base + erow, NNODE - 1);
            const int g = g_s[erow];
#pragma unroll
            for (int nt = 0; nt < 2; ++nt) {
                const int col = w*32 + nt*16 + r16;
                const float gm = film[(size_t)g*256 + col];
                const float bt = film[(size_t)g*256 + 128 + col];
                const float hv = h[(size_t)nc * HID + col];
                acc2[mt][nt][r] = hv + fmaf(gm, acc2[mt][nt][r], bt);
            }
        }

    // ---- LayerNorm: mean ----
#pragma unroll
    for (int mt = 0; mt < 4; ++mt)
#pragma unroll
        for (int r = 0; r < 4; ++r) {
            float p = acc2[mt][0][r] + acc2[mt][1][r];
#pragma unroll
            for (int s = 1; s < 16; s <<= 1) p += __shfl_xor(p, s, 16);
            if (r16 == 0) red[w][mt*16 + g4*4 + r] = p;
        }
    __syncthreads();
    if (tid < 64) mu_s[tid] = (red[0][tid] + red[1][tid] + red[2][tid] + red[3][tid]) * (1.f / 128.f);
    __syncthreads();

    // ---- variance ----
#pragma unroll
    for (int mt = 0; mt < 4; ++mt)
#pragma unroll
        for (int r = 0; r < 4; ++r) {
            const float m = mu_s[mt*16 + g4*4 + r];
            const float d0 = acc2[mt][0][r] - m, d1 = acc2[mt][1][r] - m;
            float p = d0*d0 + d1*d1;
#pragma unroll
            for (int s = 1; s < 16; s <<= 1) p += __shfl_xor(p, s, 16);
            if (r16 == 0) red[w][mt*16 + g4*4 + r] = p;
        }
    __syncthreads();
    if (tid < 64) {
        const float var = (red[0][tid] + red[1][tid] + red[2][tid] + red[3][tid]) * (1.f / 128.f);
        rs_s[tid] = 1.0f / sqrtf(var + 1e-5f);
    }
    __syncthreads();

    // ---- write ----
    const float lg0 = lng[w*32 + r16], lb0 = lnb[w*32 + r16];
    const float lg1 = lng[w*32 + 16 + r16], lb1 = lnb[w*32 + 16 + r16];
#pragma unroll
    for (int mt = 0; mt < 4; ++mt)
#pragma unroll
        for (int r = 0; r < 4; ++r) {
            const int erow = mt*16 + g4*4 + r;
            const int n = base + erow;
            if (n < NNODE) {
                const float m = mu_s[erow], rs = rs_s[erow];
                out_h[(size_t)n * HID + w*32 + r16]      = (acc2[mt][0][r] - m) * rs * lg0 + lb0;
                out_h[(size_t)n * HID + w*32 + 16 + r16] = (acc2[mt][1][r] - m) * rs * lg1 + lb1;
            }
        }
}

// ---------------------------------------------------------------------------
extern "C" void kernel_launch(void* const* d_in, const int* in_sizes, int n_in,
                              void* d_out, int out_size, void* d_ws, size_t ws_size,
                              hipStream_t stream) {
    const float* h    = (const float*)d_in[0];
    const float* pos  = (const float*)d_in[1];
    const float* ea   = (const float*)d_in[2];
    const float* cond = (const float*)d_in[3];
    const int*   eidx = (const int*)d_in[4];
    const int*   batch= (const int*)d_in[5];
    const float* W1   = (const float*)d_in[6];
    const float* b1   = (const float*)d_in[7];
    const float* W2   = (const float*)d_in[8];
    const float* b2   = (const float*)d_in[9];
    const float* Wc1  = (const float*)d_in[10];
    const float* bc1  = (const float*)d_in[11];
    const float* Wc2  = (const float*)d_in[12];
    const float* Wn1  = (const float*)d_in[13];
    const float* bn1  = (const float*)d_in[14];
    const float* Wn2  = (const float*)d_in[15];
    const float* bn2  = (const float*)d_in[16];
    const float* Wf   = (const float*)d_in[17];
    const float* bf   = (const float*)d_in[18];
    const float* lng  = (const float*)d_in[19];
    const float* lnb  = (const float*)d_in[20];

    float* out_h   = (float*)d_out;                        // [N,128]
    float* out_pos = out_h + (size_t)NNODE * HID;          // [N,3]
    float* agg_msg = (float*)d_ws;                         // [N,128]  25.6 MB
    float* film    = agg_msg + (size_t)NNODE * HID;        // [64,256] 64 KB
    f16*   W1p     = (f16*)(film + 64 * 256);              // packed f16 weights
    f16*   W2p     = W1p  + (size_t)4608 * 8;              // W1: 9 ktiles
    f16*   Wc1p    = W2p  + (size_t)2048 * 8;              // W2: 4 ktiles
    f16*   Wn1p    = Wc1p + (size_t)2048 * 8;              // Wc1: 4 ktiles
    f16*   Wn2p    = Wn1p + (size_t)4096 * 8;              // Wn1: 8 ktiles

    prep_kernel<<<1792, 256, 0, stream>>>(pos, agg_msg, out_pos,
                                          cond, Wf, bf, film,
                                          W1, W2, Wc1, Wn1, Wn2,
                                          W1p, W2p, Wc1p, Wn1p, Wn2p);
    edge_kernel<<<NEDGE / 64, 256, 0, stream>>>(h, pos, ea, eidx,
                                                W1p, b1, W2p, b2, Wc1p, bc1, Wc2,
                                                agg_msg, out_pos);
    node_kernel<<<(NNODE + 63) / 64, 256, 0, stream>>>(h, agg_msg, film, batch,
                                                       Wn1p, bn1, Wn2p, bn2,
                                                       lng, lnb, out_h);
}

// Round 10
// 665.383 us; speedup vs baseline: 135.5092x; 1.0130x over previous
//
#include <hip/hip_runtime.h>

#define HID 128
#define NEDGE 800000
#define NNODE 50000
#define NGRAPH 64

typedef _Float16 f16;
typedef __attribute__((ext_vector_type(8))) _Float16 f16x8;
typedef __attribute__((ext_vector_type(4))) float f32x4;

__device__ __forceinline__ float silu_f(float x) {
    return x * __frcp_rn(1.0f + __expf(-x));
}

// 32 consecutive f32 -> f16 into LDS (dst 16B-aligned)
__device__ __forceinline__ void stage32(f16* dst, const float* __restrict__ src) {
#pragma unroll
    for (int i = 0; i < 4; ++i) {
        const float4 a = reinterpret_cast<const float4*>(src)[2 * i];
        const float4 b = reinterpret_cast<const float4*>(src)[2 * i + 1];
        f16x8 v;
        v[0] = (f16)a.x; v[1] = (f16)a.y; v[2] = (f16)a.z; v[3] = (f16)a.w;
        v[4] = (f16)b.x; v[5] = (f16)b.y; v[6] = (f16)b.z; v[7] = (f16)b.w;
        reinterpret_cast<f16x8*>(dst)[i] = v;
    }
}
// T14 split: issue loads to regs early ...
__device__ __forceinline__ void reg_load32(float4* r, const float* __restrict__ src) {
#pragma unroll
    for (int i = 0; i < 8; ++i) r[i] = reinterpret_cast<const float4*>(src)[i];
}
// ... convert+write late (after the covering compute phase)
__device__ __forceinline__ void reg_store32(f16* dst, const float4* r) {
#pragma unroll
    for (int i = 0; i < 4; ++i) {
        const float4 a = r[2 * i], b = r[2 * i + 1];
        f16x8 v;
        v[0] = (f16)a.x; v[1] = (f16)a.y; v[2] = (f16)a.z; v[3] = (f16)a.w;
        v[4] = (f16)b.x; v[5] = (f16)b.y; v[6] = (f16)b.z; v[7] = (f16)b.w;
        reinterpret_cast<f16x8*>(dst)[i] = v;
    }
}

// One K=32 MFMA step over 4 M-tiles x 2 N-tiles (proven r8 core).
template <int LD>
__device__ __forceinline__ void mfma_step(f32x4 (&acc)[4][2],
                                          const f16 (*A)[LD], int kloc,
                                          const f16* __restrict__ Wp, int kt,
                                          int w, int lane) {
    const int r16 = lane & 15, g4 = lane >> 4;
    f16x8 bf[2];
#pragma unroll
    for (int nt = 0; nt < 2; ++nt)
        bf[nt] = *reinterpret_cast<const f16x8*>(
            Wp + (((size_t)kt * 8 + w * 2 + nt) * 64 + lane) * 8);
#pragma unroll
    for (int mt = 0; mt < 4; ++mt) {
        const f16x8 af = *reinterpret_cast<const f16x8*>(
            &A[mt * 16 + r16][kloc * 32 + g4 * 8]);
#pragma unroll
        for (int nt = 0; nt < 2; ++nt)
            acc[mt][nt] = __builtin_amdgcn_mfma_f32_16x16x32_f16(
                af, bf[nt], acc[mt][nt], 0, 0, 0);
    }
}

// ---------------------------------------------------------------------------
// prep: fused {film | weight packs | agg zero + pos copy} partitioned by block
// ---------------------------------------------------------------------------
__global__ __launch_bounds__(256) void prep_kernel(
    const float* __restrict__ pos, float* __restrict__ agg,
    float* __restrict__ out_pos,
    const float* __restrict__ cond, const float* __restrict__ Wf,
    const float* __restrict__ bfb, float* __restrict__ film,
    const float* __restrict__ W1, const float* __restrict__ W2,
    const float* __restrict__ Wc1, const float* __restrict__ Wn1,
    const float* __restrict__ Wn2,
    f16* __restrict__ W1p, f16* __restrict__ W2p, f16* __restrict__ Wc1p,
    f16* __restrict__ Wn1p, f16* __restrict__ Wn2p) {
    const int b = blockIdx.x;
    const int t = threadIdx.x;
    if (b < 64) {                      // ---- film (fp32 exact) ----
        const float* __restrict__ cg = cond + b * 128;
        float acc = bfb[t];
        for (int k = 0; k < 128; ++k) acc = fmaf(cg[k], Wf[k * 256 + t], acc);
        film[b * 256 + t] = acc;
        return;
    }
    if (b < 128) {                     // ---- weight packs ----
        const int pb = b - 64;
        const float* W; f16* outp; int Kreal, nchunks, cb;
        if (pb < 18)      { W = W1;  outp = W1p;  Kreal = 273; nchunks = 4608; cb = pb; }
        else if (pb < 26) { W = W2;  outp = W2p;  Kreal = 128; nchunks = 2048; cb = pb - 18; }
        else if (pb < 34) { W = Wc1; outp = Wc1p; Kreal = 128; nchunks = 2048; cb = pb - 26; }
        else if (pb < 50) { W = Wn1; outp = Wn1p; Kreal = 256; nchunks = 4096; cb = pb - 34; }
        else if (pb < 58) { W = Wn2; outp = Wn2p; Kreal = 128; nchunks = 2048; cb = pb - 50; }
        else return;
        const int c = cb * 256 + t;
        if (c >= nchunks) return;
        const int l = c & 63;
        const int nt = (c >> 6) & 7;
        const int kt = c >> 9;
        const int col = nt * 16 + (l & 15);
        const int kbase = kt * 32 + ((l >> 4) << 3);
        f16x8 v;
#pragma unroll
        for (int j = 0; j < 8; ++j) {
            const int kr = kbase + j;
            v[j] = (kr < Kreal) ? (f16)W[(size_t)kr * HID + col] : (f16)0.f;
        }
        *reinterpret_cast<f16x8*>(outp + (size_t)c * 8) = v;
        return;
    }
    // ---- init: zero agg, copy pos -> out_pos ----
    const int tid = (b - 128) * 256 + t;
    const int stride = (gridDim.x - 128) * 256;
    float4* a4 = reinterpret_cast<float4*>(agg);
    const int nAgg4 = NNODE * HID / 4;
    for (int i = tid; i < nAgg4; i += stride) a4[i] = make_float4(0.f, 0.f, 0.f, 0.f);
    const float4* p4 = reinterpret_cast<const float4*>(pos);
    float4* o4 = reinterpret_cast<float4*>(out_pos);
    const int nPos4 = NNODE * 3 / 4;
    for (int i = tid; i < nPos4; i += stride) o4[i] = p4[i];
}

// ---------------------------------------------------------------------------
// edge kernel — single A-buffer, T14 reg-staged h_j, ~24KB LDS (6 blocks/CU)
// ---------------------------------------------------------------------------
__global__ __launch_bounds__(256) void edge_kernel(
    const float* __restrict__ h, const float* __restrict__ pos,
    const float* __restrict__ edge_attr, const int* __restrict__ eidx,
    const f16* __restrict__ W1p, const float* __restrict__ b1,
    const f16* __restrict__ W2p, const float* __restrict__ b2,
    const f16* __restrict__ Wc1p, const float* __restrict__ bc1,
    const float* __restrict__ Wc2,
    float* __restrict__ agg_msg, float* __restrict__ out_pos) {
    __shared__ f16 A[64][136];        // h_i -> h_j -> m -> m_ij
    __shared__ f16 Atl[64][40];       // tail: d2 | edge_attr | 0-pad
    __shared__ float relx[64], rely[64], relz[64], d2s[64];
    __shared__ int ni_s[64];
    __shared__ float cw_part[4][64];

    const int tid = threadIdx.x;
    const int lane = tid & 63;
    const int w = tid >> 6;
    const int r16 = lane & 15;
    const int g4 = lane >> 4;
    const int se = tid >> 2, q = tid & 3;
    const int base = blockIdx.x * 64;          // NEDGE % 64 == 0

    const int gi = eidx[base + se];
    const int gj = eidx[NEDGE + base + se];

    // h_i -> LDS now; h_j -> regs (latency hidden under L1-hi GEMM)
    stage32(&A[se][q * 32], h + (size_t)gi * HID + q * 32);
    float4 hjreg[8];
    reg_load32(hjreg, h + (size_t)gj * HID + q * 32);

    float d2loc = 0.f;
    if (q == 0) {
        ni_s[se] = gi;
        const float ax = pos[gi*3+0], ay = pos[gi*3+1], az = pos[gi*3+2];
        const float bx = pos[gj*3+0], by = pos[gj*3+1], bz = pos[gj*3+2];
        const float rx = ax-bx, ry = ay-by, rz = az-bz;
        relx[se] = rx; rely[se] = ry; relz[se] = rz;
        d2loc = rx*rx + ry*ry + rz*rz;
        d2s[se] = d2loc;
    }
    {   // tail cols
        f16x8 v;
#pragma unroll
        for (int j = 0; j < 8; ++j) {
            const int c = q * 8 + j;
            float val = 0.f;
            if (c == 0) val = d2loc;
            else if (c <= 16) val = edge_attr[(size_t)(base + se) * 16 + (c - 1)];
            v[j] = (f16)val;
        }
        *reinterpret_cast<f16x8*>(&Atl[se][q * 8]) = v;
    }
    __syncthreads();                                        // B1

    // ---- layer 1, part 1: h_i K-tiles + tail ----
    f32x4 acc[4][2];
#pragma unroll
    for (int nt = 0; nt < 2; ++nt) {
        const float b = b1[w * 32 + nt * 16 + r16];
#pragma unroll
        for (int mt = 0; mt < 4; ++mt) acc[mt][nt] = (f32x4){b, b, b, b};
    }
    __builtin_amdgcn_s_setprio(1);
#pragma unroll
    for (int kt = 0; kt < 4; ++kt) mfma_step<136>(acc, A, kt, W1p, kt, w, lane);
    mfma_step<40>(acc, Atl, 0, W1p, 8, w, lane);
    __builtin_amdgcn_s_setprio(0);
    __syncthreads();                                        // B2 (h_i reads done)

    reg_store32(&A[se][q * 32], hjreg);                     // h_j lands now
    __syncthreads();                                        // B3

    __builtin_amdgcn_s_setprio(1);
#pragma unroll
    for (int kt = 0; kt < 4; ++kt) mfma_step<136>(acc, A, kt, W1p, 4 + kt, w, lane);
    __builtin_amdgcn_s_setprio(0);
    __syncthreads();                                        // B4 (h_j reads done)

    // ---- m = silu(L1) -> A (C-layout) ----
#pragma unroll
    for (int mt = 0; mt < 4; ++mt)
#pragma unroll
        for (int nt = 0; nt < 2; ++nt)
#pragma unroll
            for (int r = 0; r < 4; ++r)
                A[mt*16 + g4*4 + r][w*32 + nt*16 + r16] = (f16)silu_f(acc[mt][nt][r]);
    __syncthreads();                                        // B5

    // ---- layer 2 ----
    f32x4 acc2[4][2];
#pragma unroll
    for (int nt = 0; nt < 2; ++nt) {
        const float b = b2[w * 32 + nt * 16 + r16];
#pragma unroll
        for (int mt = 0; mt < 4; ++mt) acc2[mt][nt] = (f32x4){b, b, b, b};
    }
    __builtin_amdgcn_s_setprio(1);
#pragma unroll
    for (int kt = 0; kt < 4; ++kt) mfma_step<136>(acc2, A, kt, W2p, kt, w, lane);
    __builtin_amdgcn_s_setprio(0);
    __syncthreads();                                        // B6 (m reads done)

    // ---- m_ij = silu(L2) -> A + fp32 atomic scatter ----
#pragma unroll
    for (int mt = 0; mt < 4; ++mt)
#pragma unroll
        for (int r = 0; r < 4; ++r) {
            const int e = mt*16 + g4*4 + r;
            float* am = agg_msg + (size_t)ni_s[e] * HID + w*32 + r16;
#pragma unroll
            for (int nt = 0; nt < 2; ++nt) {
                const float v = silu_f(acc2[mt][nt][r]);
                A[e][w*32 + nt*16 + r16] = (f16)v;
                atomicAdd(am + nt*16, v);
            }
        }
    __syncthreads();                                        // B7

    // ---- coord layer ----
    f32x4 acc3[4][2];
#pragma unroll
    for (int nt = 0; nt < 2; ++nt) {
        const float b = bc1[w * 32 + nt * 16 + r16];
#pragma unroll
        for (int mt = 0; mt < 4; ++mt) acc3[mt][nt] = (f32x4){b, b, b, b};
    }
    __builtin_amdgcn_s_setprio(1);
#pragma unroll
    for (int kt = 0; kt < 4; ++kt) mfma_step<136>(acc3, A, kt, Wc1p, kt, w, lane);
    __builtin_amdgcn_s_setprio(0);

    const float wc0 = Wc2[w*32 + r16], wc1 = Wc2[w*32 + 16 + r16];
#pragma unroll
    for (int mt = 0; mt < 4; ++mt)
#pragma unroll
        for (int r = 0; r < 4; ++r) {
            float p = silu_f(acc3[mt][0][r]) * wc0 + silu_f(acc3[mt][1][r]) * wc1;
#pragma unroll
            for (int s = 1; s < 16; s <<= 1) p += __shfl_xor(p, s, 16);
            if (r16 == 0) cw_part[w][mt*16 + g4*4 + r] = p;
        }
    __syncthreads();                                        // B8

    if (tid < 64) {
        const int e = tid;
        const float cwf = cw_part[0][e] + cw_part[1][e] + cw_part[2][e] + cw_part[3][e];
        const float sc = cwf / sqrtf(d2s[e] + 1e-8f);
        float* op = out_pos + (size_t)ni_s[e] * 3;
        atomicAdd(op + 0, relx[e] * sc);
        atomicAdd(op + 1, rely[e] * sc);
        atomicAdd(op + 2, relz[e] * sc);
    }
}

// ---------------------------------------------------------------------------
// node kernel — single A-buffer, T14 reg-staged agg
// ---------------------------------------------------------------------------
__global__ __launch_bounds__(256) void node_kernel(
    const float* __restrict__ h, const float* __restrict__ agg_msg,
    const float* __restrict__ film, const int* __restrict__ batch,
    const f16* __restrict__ Wn1p, const float* __restrict__ bn1,
    const f16* __restrict__ Wn2p, const float* __restrict__ bn2,
    const float* __restrict__ lng, const float* __restrict__ lnb,
    float* __restrict__ out_h) {
    __shared__ f16 A[64][136];      // h -> agg -> u
    __shared__ int g_s[64];
    __shared__ float red[4][64];
    __shared__ float mu_s[64], rs_s[64];

    const int tid = threadIdx.x;
    const int lane = tid & 63;
    const int w = tid >> 6;
    const int r16 = lane & 15;
    const int g4 = lane >> 4;
    const int se = tid >> 2, q = tid & 3;
    const int base = blockIdx.x * 64;

    const int n_se = min(base + se, NNODE - 1);
    if (q == 0) g_s[se] = batch[n_se];
    stage32(&A[se][q * 32], h + (size_t)n_se * HID + q * 32);
    float4 agreg[8];
    reg_load32(agreg, agg_msg + (size_t)n_se * HID + q * 32);
    __syncthreads();

    f32x4 acc[4][2];
#pragma unroll
    for (int nt = 0; nt < 2; ++nt) {
        const float b = bn1[w * 32 + nt * 16 + r16];
#pragma unroll
        for (int mt = 0; mt < 4; ++mt) acc[mt][nt] = (f32x4){b, b, b, b};
    }
    __builtin_amdgcn_s_setprio(1);
#pragma unroll
    for (int kt = 0; kt < 4; ++kt) mfma_step<136>(acc, A, kt, Wn1p, kt, w, lane);
    __builtin_amdgcn_s_setprio(0);
    __syncthreads();

    reg_store32(&A[se][q * 32], agreg);
    __syncthreads();
    __builtin_amdgcn_s_setprio(1);
#pragma unroll
    for (int kt = 0; kt < 4; ++kt) mfma_step<136>(acc, A, kt, Wn1p, 4 + kt, w, lane);
    __builtin_amdgcn_s_setprio(0);
    __syncthreads();

    // u = silu -> A
#pragma unroll
    for (int mt = 0; mt < 4; ++mt)
#pragma unroll
        for (int nt = 0; nt < 2; ++nt)
#pragma unroll
            for (int r = 0; r < 4; ++r)
                A[mt*16 + g4*4 + r][w*32 + nt*16 + r16] = (f16)silu_f(acc[mt][nt][r]);
    __syncthreads();

    f32x4 acc2[4][2];
#pragma unroll
    for (int nt = 0; nt < 2; ++nt) {
        const float b = bn2[w * 32 + nt * 16 + r16];
#pragma unroll
        for (int mt = 0; mt < 4; ++mt) acc2[mt][nt] = (f32x4){b, b, b, b};
    }
    __builtin_amdgcn_s_setprio(1);
#pragma unroll
    for (int kt = 0; kt < 4; ++kt) mfma_step<136>(acc2, A, kt, Wn2p, kt, w, lane);
    __builtin_amdgcn_s_setprio(0);

    // ---- FiLM + residual ----
#pragma unroll
    for (int mt = 0; mt < 4; ++mt)
#pragma unroll
        for (int r = 0; r < 4; ++r) {
            const int erow = mt*16 + g4*4 + r;
            const int nc = min(base + erow, NNODE - 1);
            const int g = g_s[erow];
#pragma unroll
            for (int nt = 0; nt < 2; ++nt) {
                const int col = w*32 + nt*16 + r16;
                const float gm = film[(size_t)g*256 + col];
                const float bt = film[(size_t)g*256 + 128 + col];
                const float hv = h[(size_t)nc * HID + col];
                acc2[mt][nt][r] = hv + fmaf(gm, acc2[mt][nt][r], bt);
            }
        }

    // ---- LayerNorm: mean ----
#pragma unroll
    for (int mt = 0; mt < 4; ++mt)
#pragma unroll
        for (int r = 0; r < 4; ++r) {
            float p = acc2[mt][0][r] + acc2[mt][1][r];
#pragma unroll
            for (int s = 1; s < 16; s <<= 1) p += __shfl_xor(p, s, 16);
            if (r16 == 0) red[w][mt*16 + g4*4 + r] = p;
        }
    __syncthreads();
    if (tid < 64) mu_s[tid] = (red[0][tid] + red[1][tid] + red[2][tid] + red[3][tid]) * (1.f / 128.f);
    __syncthreads();

    // ---- variance ----
#pragma unroll
    for (int mt = 0; mt < 4; ++mt)
#pragma unroll
        for (int r = 0; r < 4; ++r) {
            const float m = mu_s[mt*16 + g4*4 + r];
            const float d0 = acc2[mt][0][r] - m, d1 = acc2[mt][1][r] - m;
            float p = d0*d0 + d1*d1;
#pragma unroll
            for (int s = 1; s < 16; s <<= 1) p += __shfl_xor(p, s, 16);
            if (r16 == 0) red[w][mt*16 + g4*4 + r] = p;
        }
    __syncthreads();
    if (tid < 64) {
        const float var = (red[0][tid] + red[1][tid] + red[2][tid] + red[3][tid]) * (1.f / 128.f);
        rs_s[tid] = 1.0f / sqrtf(var + 1e-5f);
    }
    __syncthreads();

    // ---- write ----
    const float lg0 = lng[w*32 + r16], lb0 = lnb[w*32 + r16];
    const float lg1 = lng[w*32 + 16 + r16], lb1 = lnb[w*32 + 16 + r16];
#pragma unroll
    for (int mt = 0; mt < 4; ++mt)
#pragma unroll
        for (int r = 0; r < 4; ++r) {
            const int erow = mt*16 + g4*4 + r;
            const int n = base + erow;
            if (n < NNODE) {
                const float m = mu_s[erow], rs = rs_s[erow];
                out_h[(size_t)n * HID + w*32 + r16]      = (acc2[mt][0][r] - m) * rs * lg0 + lb0;
                out_h[(size_t)n * HID + w*32 + 16 + r16] = (acc2[mt][1][r] - m) * rs * lg1 + lb1;
            }
        }
}

// ---------------------------------------------------------------------------
extern "C" void kernel_launch(void* const* d_in, const int* in_sizes, int n_in,
                              void* d_out, int out_size, void* d_ws, size_t ws_size,
                              hipStream_t stream) {
    const float* h    = (const float*)d_in[0];
    const float* pos  = (const float*)d_in[1];
    const float* ea   = (const float*)d_in[2];
    const float* cond = (const float*)d_in[3];
    const int*   eidx = (const int*)d_in[4];
    const int*   batch= (const int*)d_in[5];
    const float* W1   = (const float*)d_in[6];
    const float* b1   = (const float*)d_in[7];
    const float* W2   = (const float*)d_in[8];
    const float* b2   = (const float*)d_in[9];
    const float* Wc1  = (const float*)d_in[10];
    const float* bc1  = (const float*)d_in[11];
    const float* Wc2  = (const float*)d_in[12];
    const float* Wn1  = (const float*)d_in[13];
    const float* bn1  = (const float*)d_in[14];
    const float* Wn2  = (const float*)d_in[15];
    const float* bn2  = (const float*)d_in[16];
    const float* Wf   = (const float*)d_in[17];
    const float* bf   = (const float*)d_in[18];
    const float* lng  = (const float*)d_in[19];
    const float* lnb  = (const float*)d_in[20];

    float* out_h   = (float*)d_out;                        // [N,128]
    float* out_pos = out_h + (size_t)NNODE * HID;          // [N,3]
    float* agg_msg = (float*)d_ws;                         // [N,128]  25.6 MB
    float* film    = agg_msg + (size_t)NNODE * HID;        // [64,256] 64 KB
    f16*   W1p     = (f16*)(film + 64 * 256);              // packed f16 weights
    f16*   W2p     = W1p  + (size_t)4608 * 8;
    f16*   Wc1p    = W2p  + (size_t)2048 * 8;
    f16*   Wn1p    = Wc1p + (size_t)2048 * 8;
    f16*   Wn2p    = Wn1p + (size_t)4096 * 8;

    prep_kernel<<<1792, 256, 0, stream>>>(pos, agg_msg, out_pos,
                                          cond, Wf, bf, film,
                                          W1, W2, Wc1, Wn1, Wn2,
                                          W1p, W2p, Wc1p, Wn1p, Wn2p);
    edge_kernel<<<NEDGE / 64, 256, 0, stream>>>(h, pos, ea, eidx,
                                                W1p, b1, W2p, b2, Wc1p, bc1, Wc2,
                                                agg_msg, out_pos);
    node_kernel<<<(NNODE + 63) / 64, 256, 0, stream>>>(h, agg_msg, film, batch,
                                                       Wn1p, bn1, Wn2p, bn2,
                                                       lng, lnb, out_h);
}